// Round 1
// baseline (301.616 us; speedup 1.0000x reference)
//
#include <hip/hip_runtime.h>

// Problem constants (from reference setup_inputs): B=32, T=1000, I=256, H=512
#define BATCH 32
#define TSTEPS 1000
#define KDIM 256
#define HDIM 512

#define ALPHA_MIN_F 0.8187307530779818f
#define ALPHA_MAX_F 0.9607894391523232f

// ---------------------------------------------------------------------------
// Kernel 1: Wx[m][n] = sum_k x[m][k] * W[n][k]   (M=32000, K=256, N=512)
// Both operands are K-contiguous ("NT" gemm) -> coalesced global loads.
// 64x64 tile, BK=32, 256 threads, 4x4 micro-tile, K-major LDS (transpose on
// write) so inner-loop ds_read_b128 is broadcast/conflict-free.
// ---------------------------------------------------------------------------
__global__ __launch_bounds__(256) void gemm_xwT(const float* __restrict__ x,
                                                const float* __restrict__ W,
                                                float* __restrict__ wx) {
  __shared__ float As[32][64];  // [k][m]
  __shared__ float Bs[32][64];  // [k][n]
  const int m0 = blockIdx.x * 64;
  const int n0 = blockIdx.y * 64;
  const int tid = threadIdx.x;
  const int tx = tid & 15;       // n quad
  const int ty = tid >> 4;       // m quad
  const int lr = tid >> 2;       // load row 0..63
  const int lk = (tid & 3) * 8;  // load k offset 0,8,16,24

  float acc[4][4] = {};

  for (int k0 = 0; k0 < KDIM; k0 += 32) {
    const float4* ap =
        reinterpret_cast<const float4*>(x + (size_t)(m0 + lr) * KDIM + k0 + lk);
    const float4* bp =
        reinterpret_cast<const float4*>(W + (size_t)(n0 + lr) * KDIM + k0 + lk);
    float4 a0 = ap[0], a1 = ap[1];
    float4 b0 = bp[0], b1 = bp[1];
    __syncthreads();  // protect previous iteration's LDS reads
    As[lk + 0][lr] = a0.x; As[lk + 1][lr] = a0.y;
    As[lk + 2][lr] = a0.z; As[lk + 3][lr] = a0.w;
    As[lk + 4][lr] = a1.x; As[lk + 5][lr] = a1.y;
    As[lk + 6][lr] = a1.z; As[lk + 7][lr] = a1.w;
    Bs[lk + 0][lr] = b0.x; Bs[lk + 1][lr] = b0.y;
    Bs[lk + 2][lr] = b0.z; Bs[lk + 3][lr] = b0.w;
    Bs[lk + 4][lr] = b1.x; Bs[lk + 5][lr] = b1.y;
    Bs[lk + 6][lr] = b1.z; Bs[lk + 7][lr] = b1.w;
    __syncthreads();
#pragma unroll
    for (int k = 0; k < 32; ++k) {
      float4 av = *reinterpret_cast<const float4*>(&As[k][ty * 4]);
      float4 bv = *reinterpret_cast<const float4*>(&Bs[k][tx * 4]);
      float am[4] = {av.x, av.y, av.z, av.w};
      float bn[4] = {bv.x, bv.y, bv.z, bv.w};
#pragma unroll
      for (int i = 0; i < 4; ++i)
#pragma unroll
        for (int j = 0; j < 4; ++j)
          acc[i][j] = fmaf(am[i], bn[j], acc[i][j]);
    }
  }
#pragma unroll
  for (int i = 0; i < 4; ++i) {
    float4 o = make_float4(acc[i][0], acc[i][1], acc[i][2], acc[i][3]);
    *reinterpret_cast<float4*>(wx + (size_t)(m0 + ty * 4 + i) * HDIM + n0 +
                               tx * 4) = o;
  }
}

// ---------------------------------------------------------------------------
// Kernel 2: the sequential RLIF scan. One wave (64 lanes) per batch element;
// lane l owns channels {4l..4l+3} and {256+4l..256+4l+3}. No barriers:
// the spike pattern is shared wave-internally via __ballot. The recurrent
// term st @ Vz is computed sparsely (spikes are binary and typically absent).
// Depth-4 register prefetch pipeline on the Wx stream; loop unrolled by 4 so
// all pipeline/array indices are compile-time (avoid scratch).
// NOTE: wxbuf may alias out (when ws_size is too small) -> no __restrict__
// on those two.
// ---------------------------------------------------------------------------
__global__ __launch_bounds__(64) void rlif_scan(const float* wxbuf,
                                                const float* __restrict__ V,
                                                const float* __restrict__ alpha,
                                                const float* __restrict__ vthr,
                                                float* out) {
  const int b = blockIdx.x;
  const int l = threadIdx.x;
  const int h0 = 4 * l;        // lower-half base channel
  const int h1 = 256 + 4 * l;  // upper-half base channel

  float4 al0 = *reinterpret_cast<const float4*>(alpha + h0);
  float4 al1 = *reinterpret_cast<const float4*>(alpha + h1);
  float4 th0 = *reinterpret_cast<const float4*>(vthr + h0);
  float4 th1 = *reinterpret_cast<const float4*>(vthr + h1);

  float a[8] = {al0.x, al0.y, al0.z, al0.w, al1.x, al1.y, al1.z, al1.w};
  float th[8] = {th0.x, th0.y, th0.z, th0.w, th1.x, th1.y, th1.z, th1.w};
  float na[8], u[8], s[8], r[8];
#pragma unroll
  for (int j = 0; j < 8; ++j) {
    float c = fminf(fmaxf(a[j], ALPHA_MIN_F), ALPHA_MAX_F);
    a[j] = c;
    na[j] = 1.0f - c;
    u[j] = 0.0f;
    s[j] = 0.0f;
    r[j] = 0.0f;
  }

  const float* wb = wxbuf + (size_t)b * TSTEPS * HDIM;
  float* ob = out + (size_t)b * TSTEPS * HDIM;

  // Prefetch pipeline, depth 4.
  float4 p0[4], p1[4];
#pragma unroll
  for (int d = 0; d < 4; ++d) {
    p0[d] = *reinterpret_cast<const float4*>(wb + (size_t)d * HDIM + h0);
    p1[d] = *reinterpret_cast<const float4*>(wb + (size_t)d * HDIM + h1);
  }

  for (int t0 = 0; t0 < TSTEPS; t0 += 4) {
#pragma unroll
    for (int ts = 0; ts < 4; ++ts) {
      const int t = t0 + ts;
      float w8[8] = {p0[ts].x, p0[ts].y, p0[ts].z, p0[ts].w,
                     p1[ts].x, p1[ts].y, p1[ts].z, p1[ts].w};
      // refill this pipeline slot (clamped address; value unused past end)
      int tpre = t + 4;
      if (tpre > TSTEPS - 1) tpre = TSTEPS - 1;
      p0[ts] = *reinterpret_cast<const float4*>(wb + (size_t)tpre * HDIM + h0);
      p1[ts] = *reinterpret_cast<const float4*>(wb + (size_t)tpre * HDIM + h1);

      // u = a*(u - s) + (1-a)*(wx + r);  s = u > thr
#pragma unroll
      for (int j = 0; j < 8; ++j) {
        float un = fmaf(a[j], u[j] - s[j], na[j] * (w8[j] + r[j]));
        u[j] = un;
        s[j] = (un > th[j]) ? 1.0f : 0.0f;
      }
      *reinterpret_cast<float4*>(ob + (size_t)t * HDIM + h0) =
          make_float4(s[0], s[1], s[2], s[3]);
      *reinterpret_cast<float4*>(ob + (size_t)t * HDIM + h1) =
          make_float4(s[4], s[5], s[6], s[7]);

      // Recurrent drive for the NEXT step: r = s @ Vz (sparse, rare).
      float ssum = s[0] + s[1] + s[2] + s[3] + s[4] + s[5] + s[6] + s[7];
      unsigned long long anym = __ballot(ssum != 0.0f);
      if (anym != 0ull) {
        unsigned long long mk[8];
#pragma unroll
        for (int j = 0; j < 8; ++j) mk[j] = __ballot(s[j] != 0.0f);
        float rr[8] = {0.f, 0.f, 0.f, 0.f, 0.f, 0.f, 0.f, 0.f};
#pragma unroll
        for (int j2 = 0; j2 < 8; ++j2) {
          unsigned long long m = mk[j2];
          while (m) {  // wave-uniform loop (masks identical on all lanes)
            int src = __builtin_ctzll(m);
            m &= m - 1;
            int hin = (j2 < 4) ? (src * 4 + j2) : (256 + src * 4 + (j2 - 4));
            const float* vrow = V + (size_t)hin * HDIM;
            float4 v0 = *reinterpret_cast<const float4*>(vrow + h0);
            float4 v1 = *reinterpret_cast<const float4*>(vrow + h1);
            float vv[8] = {v0.x, v0.y, v0.z, v0.w, v1.x, v1.y, v1.z, v1.w};
#pragma unroll
            for (int j = 0; j < 8; ++j) {
              int hj = (j < 4) ? (h0 + j) : (h1 + j - 4);
              rr[j] += (hj == hin) ? 0.0f : vv[j];  // zeroed diagonal
            }
          }
        }
#pragma unroll
        for (int j = 0; j < 8; ++j) r[j] = rr[j];
      } else {
#pragma unroll
        for (int j = 0; j < 8; ++j) r[j] = 0.0f;
      }
    }
  }
}

extern "C" void kernel_launch(void* const* d_in, const int* in_sizes, int n_in,
                              void* d_out, int out_size, void* d_ws,
                              size_t ws_size, hipStream_t stream) {
  const float* x = (const float*)d_in[0];      // [32,1000,256]
  const float* W = (const float*)d_in[1];      // [512,256]
  const float* V = (const float*)d_in[2];      // [512,512]
  const float* alpha = (const float*)d_in[3];  // [512]
  const float* vthr = (const float*)d_in[4];   // [512]
  float* out = (float*)d_out;                  // [32,1000,512]

  const size_t need = (size_t)BATCH * TSTEPS * HDIM * sizeof(float);
  // Stage Wx in d_ws if it fits; otherwise stage it in d_out (the scan reads
  // wx[t] before overwriting that exact location with s[t] -> safe, and the
  // GEMM rewrites it at the start of every launch -> replay-deterministic).
  float* wx = (ws_size >= need) ? (float*)d_ws : out;

  dim3 ggrid(BATCH * TSTEPS / 64, HDIM / 64);  // (500, 8)
  hipLaunchKernelGGL(gemm_xwT, ggrid, dim3(256), 0, stream, x, W, wx);
  hipLaunchKernelGGL(rlif_scan, dim3(BATCH), dim3(64), 0, stream, wx, V, alpha,
                     vthr, out);
}

// Round 3
// 198.025 us; speedup vs baseline: 1.5231x; 1.5231x over previous
//
#include <hip/hip_runtime.h>

// Problem constants (from reference setup_inputs): B=32, T=1000, I=256, H=512
#define BATCH 32
#define TSTEPS 1000
#define KDIM 256
#define HDIM 512
#define PFD 25  // prefetch depth; TSTEPS % PFD == 0

#define ALPHA_MIN_F 0.8187307530779818f
#define ALPHA_MAX_F 0.9607894391523232f

__global__ void init_fs(int* fs) {
  if (threadIdx.x < BATCH) fs[threadIdx.x] = TSTEPS;
}

// ---------------------------------------------------------------------------
// Kernel 1 (PROVEN, round-1 verbatim): Wx[m][n] = sum_k x[m][k] * W[n][k]
// ---------------------------------------------------------------------------
__global__ __launch_bounds__(256) void gemm_xwT(const float* __restrict__ x,
                                                const float* __restrict__ W,
                                                float* __restrict__ wx) {
  __shared__ float As[32][64];  // [k][m]
  __shared__ float Bs[32][64];  // [k][n]
  const int m0 = blockIdx.x * 64;
  const int n0 = blockIdx.y * 64;
  const int tid = threadIdx.x;
  const int tx = tid & 15;
  const int ty = tid >> 4;
  const int lr = tid >> 2;
  const int lk = (tid & 3) * 8;

  float acc[4][4] = {};
  for (int k0 = 0; k0 < KDIM; k0 += 32) {
    const float4* ap =
        reinterpret_cast<const float4*>(x + (size_t)(m0 + lr) * KDIM + k0 + lk);
    const float4* bp =
        reinterpret_cast<const float4*>(W + (size_t)(n0 + lr) * KDIM + k0 + lk);
    float4 a0 = ap[0], a1 = ap[1];
    float4 b0 = bp[0], b1 = bp[1];
    __syncthreads();
    As[lk + 0][lr] = a0.x; As[lk + 1][lr] = a0.y;
    As[lk + 2][lr] = a0.z; As[lk + 3][lr] = a0.w;
    As[lk + 4][lr] = a1.x; As[lk + 5][lr] = a1.y;
    As[lk + 6][lr] = a1.z; As[lk + 7][lr] = a1.w;
    Bs[lk + 0][lr] = b0.x; Bs[lk + 1][lr] = b0.y;
    Bs[lk + 2][lr] = b0.z; Bs[lk + 3][lr] = b0.w;
    Bs[lk + 4][lr] = b1.x; Bs[lk + 5][lr] = b1.y;
    Bs[lk + 6][lr] = b1.z; Bs[lk + 7][lr] = b1.w;
    __syncthreads();
#pragma unroll
    for (int k = 0; k < 32; ++k) {
      float4 av = *reinterpret_cast<const float4*>(&As[k][ty * 4]);
      float4 bv = *reinterpret_cast<const float4*>(&Bs[k][tx * 4]);
      float am[4] = {av.x, av.y, av.z, av.w};
      float bn[4] = {bv.x, bv.y, bv.z, bv.w};
#pragma unroll
      for (int i = 0; i < 4; ++i)
#pragma unroll
        for (int j = 0; j < 4; ++j) acc[i][j] = fmaf(am[i], bn[j], acc[i][j]);
    }
  }
#pragma unroll
  for (int i = 0; i < 4; ++i) {
    float4 o = make_float4(acc[i][0], acc[i][1], acc[i][2], acc[i][3]);
    *reinterpret_cast<float4*>(wx + (size_t)(m0 + ty * 4 + i) * HDIM + n0 +
                               tx * 4) = o;
  }
}

// ---------------------------------------------------------------------------
// Kernel 2: parallel per-channel scan (r=0). One thread per (b,h). Bitwise
// identical to the coupled dynamics up to and including the batch's first true
// spike t* (all s and r are zero before it; the spiking step itself uses only
// pre-spike state). Records t* per batch via atomicMin. Coalesced 256B/wave
// loads+stores; depth-25 register prefetch (statically indexed, full unroll).
// ---------------------------------------------------------------------------
__global__ __launch_bounds__(64) void phase1(const float* __restrict__ wx,
                                             const float* __restrict__ alpha,
                                             const float* __restrict__ vthr,
                                             float* __restrict__ out,
                                             int* __restrict__ fs) {
  const int b = blockIdx.x >> 3;
  const int h = ((blockIdx.x & 7) << 6) + threadIdx.x;
  const float a = fminf(fmaxf(alpha[h], ALPHA_MIN_F), ALPHA_MAX_F);
  const float na = 1.0f - a;
  const float th = vthr[h];
  const float* wp = wx + (size_t)b * TSTEPS * HDIM + h;
  float* op = out + (size_t)b * TSTEPS * HDIM + h;

  float u = 0.f, s = 0.f;
  int first = TSTEPS;

  float pf[PFD];
#pragma unroll
  for (int d = 0; d < PFD; ++d) pf[d] = wp[(size_t)d * HDIM];

  for (int t0 = 0; t0 < TSTEPS; t0 += PFD) {
#pragma unroll
    for (int ts = 0; ts < PFD; ++ts) {
      const int t = t0 + ts;
      const float w = pf[ts];
      int tp = t + PFD;
      if (tp > TSTEPS - 1) tp = TSTEPS - 1;  // clamped harmless tail reload
      pf[ts] = wp[(size_t)tp * HDIM];
      u = fmaf(a, u - s, na * w);
      s = (u > th) ? 1.0f : 0.0f;
      op[(size_t)t * HDIM] = s;
      if (s != 0.0f && first == TSTEPS) {
        first = t;
        atomicMin(&fs[b], t);
      }
    }
  }
}

// ---------------------------------------------------------------------------
// Full coupled scan body (round-1 verbatim): one wave per batch, sparse s@Vz
// via ballot. Used ungated (tiny-ws tier) and gated-on-first-spike (fallback).
// ---------------------------------------------------------------------------
static __device__ __forceinline__ void scan_body(const float* wxbuf,
                                                 const float* __restrict__ V,
                                                 const float* __restrict__ alpha,
                                                 const float* __restrict__ vthr,
                                                 float* out, int b) {
  const int l = threadIdx.x;
  const int h0 = 4 * l;
  const int h1 = 256 + 4 * l;

  float4 al0 = *reinterpret_cast<const float4*>(alpha + h0);
  float4 al1 = *reinterpret_cast<const float4*>(alpha + h1);
  float4 th0 = *reinterpret_cast<const float4*>(vthr + h0);
  float4 th1 = *reinterpret_cast<const float4*>(vthr + h1);
  float a[8] = {al0.x, al0.y, al0.z, al0.w, al1.x, al1.y, al1.z, al1.w};
  float th[8] = {th0.x, th0.y, th0.z, th0.w, th1.x, th1.y, th1.z, th1.w};
  float na[8], u[8], s[8], r[8];
#pragma unroll
  for (int j = 0; j < 8; ++j) {
    float c = fminf(fmaxf(a[j], ALPHA_MIN_F), ALPHA_MAX_F);
    a[j] = c; na[j] = 1.0f - c;
    u[j] = 0.f; s[j] = 0.f; r[j] = 0.f;
  }
  const float* wb = wxbuf + (size_t)b * TSTEPS * HDIM;
  float* ob = out + (size_t)b * TSTEPS * HDIM;
  float4 p0[4], p1[4];
#pragma unroll
  for (int d = 0; d < 4; ++d) {
    p0[d] = *reinterpret_cast<const float4*>(wb + (size_t)d * HDIM + h0);
    p1[d] = *reinterpret_cast<const float4*>(wb + (size_t)d * HDIM + h1);
  }
  for (int t0 = 0; t0 < TSTEPS; t0 += 4) {
#pragma unroll
    for (int ts = 0; ts < 4; ++ts) {
      const int t = t0 + ts;
      float w8[8] = {p0[ts].x, p0[ts].y, p0[ts].z, p0[ts].w,
                     p1[ts].x, p1[ts].y, p1[ts].z, p1[ts].w};
      int tpre = t + 4;
      if (tpre > TSTEPS - 1) tpre = TSTEPS - 1;
      p0[ts] = *reinterpret_cast<const float4*>(wb + (size_t)tpre * HDIM + h0);
      p1[ts] = *reinterpret_cast<const float4*>(wb + (size_t)tpre * HDIM + h1);
#pragma unroll
      for (int j = 0; j < 8; ++j) {
        float un = fmaf(a[j], u[j] - s[j], na[j] * (w8[j] + r[j]));
        u[j] = un;
        s[j] = (un > th[j]) ? 1.0f : 0.0f;
      }
      *reinterpret_cast<float4*>(ob + (size_t)t * HDIM + h0) =
          make_float4(s[0], s[1], s[2], s[3]);
      *reinterpret_cast<float4*>(ob + (size_t)t * HDIM + h1) =
          make_float4(s[4], s[5], s[6], s[7]);
      float ssum = s[0] + s[1] + s[2] + s[3] + s[4] + s[5] + s[6] + s[7];
      unsigned long long anym = __ballot(ssum != 0.0f);
      if (anym != 0ull) {
        unsigned long long mk[8];
#pragma unroll
        for (int j = 0; j < 8; ++j) mk[j] = __ballot(s[j] != 0.0f);
        float rr[8] = {0.f, 0.f, 0.f, 0.f, 0.f, 0.f, 0.f, 0.f};
#pragma unroll
        for (int j2 = 0; j2 < 8; ++j2) {
          unsigned long long m = mk[j2];
          while (m) {  // wave-uniform (masks identical on all lanes)
            int src = __builtin_ctzll(m);
            m &= m - 1;
            int hin = (j2 < 4) ? (src * 4 + j2) : (256 + src * 4 + (j2 - 4));
            const float* vrow = V + (size_t)hin * HDIM;
            float4 v0 = *reinterpret_cast<const float4*>(vrow + h0);
            float4 v1 = *reinterpret_cast<const float4*>(vrow + h1);
            float vv[8] = {v0.x, v0.y, v0.z, v0.w, v1.x, v1.y, v1.z, v1.w};
#pragma unroll
            for (int j = 0; j < 8; ++j) {
              int hj = (j < 4) ? (h0 + j) : (h1 + j - 4);
              rr[j] += (hj == hin) ? 0.0f : vv[j];  // zeroed diagonal
            }
          }
        }
#pragma unroll
        for (int j = 0; j < 8; ++j) r[j] = rr[j];
      } else {
#pragma unroll
        for (int j = 0; j < 8; ++j) r[j] = 0.0f;
      }
    }
  }
}

// Gated fallback: only batches whose first spike occurs at t <= TSTEPS-2 need
// the coupled recompute (a first spike at the last step cannot affect any
// output). For those, redo the whole batch with the validated coupled scan.
__global__ __launch_bounds__(64) void fallback_scan(
    const float* wxbuf, const float* __restrict__ V,
    const float* __restrict__ alpha, const float* __restrict__ vthr,
    float* out, const int* __restrict__ fs) {
  const int b = blockIdx.x;
  if (fs[b] >= TSTEPS - 1) return;
  scan_body(wxbuf, V, alpha, vthr, out, b);
}

// Ungated (tiny-ws tier, round-1 semantics).
__global__ __launch_bounds__(64) void rlif_scan(const float* wxbuf,
                                                const float* __restrict__ V,
                                                const float* __restrict__ alpha,
                                                const float* __restrict__ vthr,
                                                float* out) {
  scan_body(wxbuf, V, alpha, vthr, out, blockIdx.x);
}

extern "C" void kernel_launch(void* const* d_in, const int* in_sizes, int n_in,
                              void* d_out, int out_size, void* d_ws,
                              size_t ws_size, hipStream_t stream) {
  const float* x = (const float*)d_in[0];      // [32,1000,256]
  const float* W = (const float*)d_in[1];      // [512,256]
  const float* V = (const float*)d_in[2];      // [512,512]
  const float* alpha = (const float*)d_in[3];  // [512]
  const float* vthr = (const float*)d_in[4];   // [512]
  float* out = (float*)d_out;                  // [32,1000,512]

  const size_t wx_b = (size_t)BATCH * TSTEPS * HDIM * 4;  // 65,536,000

  char* ws = (char*)d_ws;
  if (ws_size >= wx_b + 128) {
    float* wx = (float*)ws;
    int* fs = (int*)(ws + wx_b);
    hipLaunchKernelGGL(init_fs, dim3(1), dim3(64), 0, stream, fs);
    hipLaunchKernelGGL(gemm_xwT, dim3(BATCH * TSTEPS / 64, HDIM / 64),
                       dim3(256), 0, stream, x, W, wx);
    hipLaunchKernelGGL(phase1, dim3(BATCH * 8), dim3(64), 0, stream, wx, alpha,
                       vthr, out, fs);
    hipLaunchKernelGGL(fallback_scan, dim3(BATCH), dim3(64), 0, stream, wx, V,
                       alpha, vthr, out, fs);
  } else {
    // Tiny-ws tier: proven round-1 path (wx in ws if it fits, else staged in
    // out; the scan reads wx[t] before overwriting it with s[t]).
    float* wx = (ws_size >= wx_b) ? (float*)ws : out;
    hipLaunchKernelGGL(gemm_xwT, dim3(BATCH * TSTEPS / 64, HDIM / 64),
                       dim3(256), 0, stream, x, W, wx);
    hipLaunchKernelGGL(rlif_scan, dim3(BATCH), dim3(64), 0, stream, wx, V,
                       alpha, vthr, out);
  }
}

// Round 4
// 184.828 us; speedup vs baseline: 1.6319x; 1.0714x over previous
//
#include <hip/hip_runtime.h>

// Problem constants (from reference setup_inputs): B=32, T=1000, I=256, H=512
#define BATCH 32
#define TSTEPS 1000
#define KDIM 256
#define HDIM 512
#define PFD 40  // prefetch depth; TSTEPS % PFD == 0 (REQUIRED: unrolled tail)

#define ALPHA_MIN_F 0.8187307530779818f
#define ALPHA_MAX_F 0.9607894391523232f

typedef __attribute__((ext_vector_type(8))) short bf16x8;  // 8 bf16 (4 VGPRs)
typedef __attribute__((ext_vector_type(4))) float f32x4;

static __device__ __forceinline__ unsigned short f2bf(float f) {
  unsigned u = __float_as_uint(f);
  u += 0x7FFF + ((u >> 16) & 1);  // round-to-nearest-even
  return (unsigned short)(u >> 16);
}
static __device__ __forceinline__ float bf2f(unsigned short s) {
  return __uint_as_float(((unsigned)s) << 16);
}

__global__ void init_fs(int* fs) {
  if (threadIdx.x < BATCH) fs[threadIdx.x] = TSTEPS;
}

// ---------------------------------------------------------------------------
// Split-cast: f32 -> (hi, lo) bf16 pair. hi = bf16(x), lo = bf16(x - hi).
// 3-term MFMA on (hi,lo) gives ~2^-18 relative error - far below any
// spike-flip threshold.
// ---------------------------------------------------------------------------
__global__ __launch_bounds__(256) void cast_split(const float* __restrict__ src,
                                                  unsigned short* __restrict__ hi,
                                                  unsigned short* __restrict__ lo,
                                                  int n4) {
  int i = blockIdx.x * 256 + threadIdx.x;
  if (i >= n4) return;
  float4 v = reinterpret_cast<const float4*>(src)[i];
  ushort4 h, l;
  h.x = f2bf(v.x); l.x = f2bf(v.x - bf2f(h.x));
  h.y = f2bf(v.y); l.y = f2bf(v.y - bf2f(h.y));
  h.z = f2bf(v.z); l.z = f2bf(v.z - bf2f(h.z));
  h.w = f2bf(v.w); l.w = f2bf(v.w - bf2f(h.w));
  reinterpret_cast<ushort4*>(hi)[i] = h;
  reinterpret_cast<ushort4*>(lo)[i] = l;
}

// ---------------------------------------------------------------------------
// MFMA GEMM: wx[m][n] = sum_k x[m][k]*W[n][k], 3-pass bf16 split (hh+lh+hl).
// mfma_f32_16x16x32_bf16 (m89-verified C/D: col=lane&15, row=4*(lane>>4)+reg).
// A and B fragments loaded with the SAME k-map (k = 8*(lane>>4) + e within
// each K=32 step) -> result is invariant to the hardware's internal k order.
// Per wave: 32 output rows x all 512 cols; A fragments register-resident.
// ---------------------------------------------------------------------------
__global__ __launch_bounds__(256, 1) void gemm_mfma(
    const unsigned short* __restrict__ xhi, const unsigned short* __restrict__ xlo,
    const unsigned short* __restrict__ whi, const unsigned short* __restrict__ wlo,
    float* __restrict__ wx) {
  const int lane = threadIdx.x & 63;
  const int wid = threadIdx.x >> 6;
  const int m0 = (blockIdx.x * 4 + wid) * 32;
  const int row = lane & 15;
  const int kg = lane >> 4;  // 0..3

  // A fragments: 2 row-tiles x 8 k-steps, hi & lo (held in regs, reused x32)
  bf16x8 ah[2][8], al[2][8];
#pragma unroll
  for (int rt = 0; rt < 2; ++rt) {
    const unsigned short* ph = xhi + (size_t)(m0 + rt * 16 + row) * KDIM + kg * 8;
    const unsigned short* pl = xlo + (size_t)(m0 + rt * 16 + row) * KDIM + kg * 8;
#pragma unroll
    for (int ks = 0; ks < 8; ++ks) {
      ah[rt][ks] = *reinterpret_cast<const bf16x8*>(ph + ks * 32);
      al[rt][ks] = *reinterpret_cast<const bf16x8*>(pl + ks * 32);
    }
  }
  const unsigned short* bhb = whi + (size_t)row * KDIM + kg * 8;
  const unsigned short* blb = wlo + (size_t)row * KDIM + kg * 8;

  for (int ct = 0; ct < 32; ++ct) {
    const int n0 = ct * 16;
    f32x4 acc0 = {0.f, 0.f, 0.f, 0.f};
    f32x4 acc1 = {0.f, 0.f, 0.f, 0.f};
#pragma unroll
    for (int ks = 0; ks < 8; ++ks) {
      bf16x8 bh = *reinterpret_cast<const bf16x8*>(bhb + (size_t)n0 * KDIM + ks * 32);
      bf16x8 bl = *reinterpret_cast<const bf16x8*>(blb + (size_t)n0 * KDIM + ks * 32);
      acc0 = __builtin_amdgcn_mfma_f32_16x16x32_bf16(ah[0][ks], bh, acc0, 0, 0, 0);
      acc1 = __builtin_amdgcn_mfma_f32_16x16x32_bf16(ah[1][ks], bh, acc1, 0, 0, 0);
      acc0 = __builtin_amdgcn_mfma_f32_16x16x32_bf16(al[0][ks], bh, acc0, 0, 0, 0);
      acc1 = __builtin_amdgcn_mfma_f32_16x16x32_bf16(al[1][ks], bh, acc1, 0, 0, 0);
      acc0 = __builtin_amdgcn_mfma_f32_16x16x32_bf16(ah[0][ks], bl, acc0, 0, 0, 0);
      acc1 = __builtin_amdgcn_mfma_f32_16x16x32_bf16(ah[1][ks], bl, acc1, 0, 0, 0);
    }
#pragma unroll
    for (int j = 0; j < 4; ++j) {
      wx[(size_t)(m0 + kg * 4 + j) * HDIM + n0 + row] = acc0[j];
      wx[(size_t)(m0 + 16 + kg * 4 + j) * HDIM + n0 + row] = acc1[j];
    }
  }
}

// ---------------------------------------------------------------------------
// Phase 1 (round-3-proven structure): per-channel uncoupled scan (r=0).
// One thread per (b,h); exact up to and including the batch's first true
// spike; records it via atomicMin. PFD=40 (1000 % 40 == 0 - the round-2
// failure was PFD=16 writing 8 OOB steps into the next batch).
// ---------------------------------------------------------------------------
__global__ __launch_bounds__(64) void phase1(const float* __restrict__ wx,
                                             const float* __restrict__ alpha,
                                             const float* __restrict__ vthr,
                                             float* __restrict__ out,
                                             int* __restrict__ fs) {
  const int b = blockIdx.x >> 3;
  const int h = ((blockIdx.x & 7) << 6) + threadIdx.x;
  const float a = fminf(fmaxf(alpha[h], ALPHA_MIN_F), ALPHA_MAX_F);
  const float na = 1.0f - a;
  const float th = vthr[h];
  const float* wp = wx + (size_t)b * TSTEPS * HDIM + h;
  float* op = out + (size_t)b * TSTEPS * HDIM + h;

  float u = 0.f, s = 0.f;
  int first = TSTEPS;

  float pf[PFD];
#pragma unroll
  for (int d = 0; d < PFD; ++d) pf[d] = wp[(size_t)d * HDIM];

  for (int t0 = 0; t0 < TSTEPS; t0 += PFD) {
#pragma unroll
    for (int ts = 0; ts < PFD; ++ts) {
      const int t = t0 + ts;
      const float w = pf[ts];
      int tp = t + PFD;
      if (tp > TSTEPS - 1) tp = TSTEPS - 1;  // clamped harmless tail reload
      pf[ts] = wp[(size_t)tp * HDIM];
      u = fmaf(a, u - s, na * w);
      s = (u > th) ? 1.0f : 0.0f;
      op[(size_t)t * HDIM] = s;
      if (s != 0.0f && first == TSTEPS) {
        first = t;
        atomicMin(&fs[b], t);
      }
    }
  }
}

// ---------------------------------------------------------------------------
// Full coupled scan body (round-1-proven): one wave per batch, sparse s@Vz
// via ballot. Used gated (fallback) and ungated (tiny-ws tier).
// ---------------------------------------------------------------------------
static __device__ __forceinline__ void scan_body(const float* wxbuf,
                                                 const float* __restrict__ V,
                                                 const float* __restrict__ alpha,
                                                 const float* __restrict__ vthr,
                                                 float* out, int b) {
  const int l = threadIdx.x;
  const int h0 = 4 * l;
  const int h1 = 256 + 4 * l;

  float4 al0 = *reinterpret_cast<const float4*>(alpha + h0);
  float4 al1 = *reinterpret_cast<const float4*>(alpha + h1);
  float4 th0 = *reinterpret_cast<const float4*>(vthr + h0);
  float4 th1 = *reinterpret_cast<const float4*>(vthr + h1);
  float a[8] = {al0.x, al0.y, al0.z, al0.w, al1.x, al1.y, al1.z, al1.w};
  float th[8] = {th0.x, th0.y, th0.z, th0.w, th1.x, th1.y, th1.z, th1.w};
  float na[8], u[8], s[8], r[8];
#pragma unroll
  for (int j = 0; j < 8; ++j) {
    float c = fminf(fmaxf(a[j], ALPHA_MIN_F), ALPHA_MAX_F);
    a[j] = c; na[j] = 1.0f - c;
    u[j] = 0.f; s[j] = 0.f; r[j] = 0.f;
  }
  const float* wb = wxbuf + (size_t)b * TSTEPS * HDIM;
  float* ob = out + (size_t)b * TSTEPS * HDIM;
  float4 p0[4], p1[4];
#pragma unroll
  for (int d = 0; d < 4; ++d) {
    p0[d] = *reinterpret_cast<const float4*>(wb + (size_t)d * HDIM + h0);
    p1[d] = *reinterpret_cast<const float4*>(wb + (size_t)d * HDIM + h1);
  }
  for (int t0 = 0; t0 < TSTEPS; t0 += 4) {
#pragma unroll
    for (int ts = 0; ts < 4; ++ts) {
      const int t = t0 + ts;
      float w8[8] = {p0[ts].x, p0[ts].y, p0[ts].z, p0[ts].w,
                     p1[ts].x, p1[ts].y, p1[ts].z, p1[ts].w};
      int tpre = t + 4;
      if (tpre > TSTEPS - 1) tpre = TSTEPS - 1;
      p0[ts] = *reinterpret_cast<const float4*>(wb + (size_t)tpre * HDIM + h0);
      p1[ts] = *reinterpret_cast<const float4*>(wb + (size_t)tpre * HDIM + h1);
#pragma unroll
      for (int j = 0; j < 8; ++j) {
        float un = fmaf(a[j], u[j] - s[j], na[j] * (w8[j] + r[j]));
        u[j] = un;
        s[j] = (un > th[j]) ? 1.0f : 0.0f;
      }
      *reinterpret_cast<float4*>(ob + (size_t)t * HDIM + h0) =
          make_float4(s[0], s[1], s[2], s[3]);
      *reinterpret_cast<float4*>(ob + (size_t)t * HDIM + h1) =
          make_float4(s[4], s[5], s[6], s[7]);
      float ssum = s[0] + s[1] + s[2] + s[3] + s[4] + s[5] + s[6] + s[7];
      unsigned long long anym = __ballot(ssum != 0.0f);
      if (anym != 0ull) {
        unsigned long long mk[8];
#pragma unroll
        for (int j = 0; j < 8; ++j) mk[j] = __ballot(s[j] != 0.0f);
        float rr[8] = {0.f, 0.f, 0.f, 0.f, 0.f, 0.f, 0.f, 0.f};
#pragma unroll
        for (int j2 = 0; j2 < 8; ++j2) {
          unsigned long long m = mk[j2];
          while (m) {  // wave-uniform (masks identical on all lanes)
            int src = __builtin_ctzll(m);
            m &= m - 1;
            int hin = (j2 < 4) ? (src * 4 + j2) : (256 + src * 4 + (j2 - 4));
            const float* vrow = V + (size_t)hin * HDIM;
            float4 v0 = *reinterpret_cast<const float4*>(vrow + h0);
            float4 v1 = *reinterpret_cast<const float4*>(vrow + h1);
            float vv[8] = {v0.x, v0.y, v0.z, v0.w, v1.x, v1.y, v1.z, v1.w};
#pragma unroll
            for (int j = 0; j < 8; ++j) {
              int hj = (j < 4) ? (h0 + j) : (h1 + j - 4);
              rr[j] += (hj == hin) ? 0.0f : vv[j];  // zeroed diagonal
            }
          }
        }
#pragma unroll
        for (int j = 0; j < 8; ++j) r[j] = rr[j];
      } else {
#pragma unroll
        for (int j = 0; j < 8; ++j) r[j] = 0.0f;
      }
    }
  }
}

// Gated fallback: only batches whose first spike is at t <= TSTEPS-2 need the
// coupled recompute (a spike at the last step cannot affect any output).
__global__ __launch_bounds__(64) void fallback_scan(
    const float* wxbuf, const float* __restrict__ V,
    const float* __restrict__ alpha, const float* __restrict__ vthr,
    float* out, const int* __restrict__ fs) {
  const int b = blockIdx.x;
  if (fs[b] >= TSTEPS - 1) return;
  scan_body(wxbuf, V, alpha, vthr, out, b);
}

// Ungated (tiny-ws tier, round-1 semantics).
__global__ __launch_bounds__(64) void rlif_scan(const float* wxbuf,
                                                const float* __restrict__ V,
                                                const float* __restrict__ alpha,
                                                const float* __restrict__ vthr,
                                                float* out) {
  scan_body(wxbuf, V, alpha, vthr, out, blockIdx.x);
}

// ---------------------------------------------------------------------------
// Tier-B f32 GEMM (round-1-proven).
// ---------------------------------------------------------------------------
__global__ __launch_bounds__(256) void gemm_xwT(const float* __restrict__ x,
                                                const float* __restrict__ W,
                                                float* __restrict__ wx) {
  __shared__ float As[32][64];
  __shared__ float Bs[32][64];
  const int m0 = blockIdx.x * 64;
  const int n0 = blockIdx.y * 64;
  const int tid = threadIdx.x;
  const int tx = tid & 15;
  const int ty = tid >> 4;
  const int lr = tid >> 2;
  const int lk = (tid & 3) * 8;

  float acc[4][4] = {};
  for (int k0 = 0; k0 < KDIM; k0 += 32) {
    const float4* ap =
        reinterpret_cast<const float4*>(x + (size_t)(m0 + lr) * KDIM + k0 + lk);
    const float4* bp =
        reinterpret_cast<const float4*>(W + (size_t)(n0 + lr) * KDIM + k0 + lk);
    float4 a0 = ap[0], a1 = ap[1];
    float4 b0 = bp[0], b1 = bp[1];
    __syncthreads();
    As[lk + 0][lr] = a0.x; As[lk + 1][lr] = a0.y;
    As[lk + 2][lr] = a0.z; As[lk + 3][lr] = a0.w;
    As[lk + 4][lr] = a1.x; As[lk + 5][lr] = a1.y;
    As[lk + 6][lr] = a1.z; As[lk + 7][lr] = a1.w;
    Bs[lk + 0][lr] = b0.x; Bs[lk + 1][lr] = b0.y;
    Bs[lk + 2][lr] = b0.z; Bs[lk + 3][lr] = b0.w;
    Bs[lk + 4][lr] = b1.x; Bs[lk + 5][lr] = b1.y;
    Bs[lk + 6][lr] = b1.z; Bs[lk + 7][lr] = b1.w;
    __syncthreads();
#pragma unroll
    for (int k = 0; k < 32; ++k) {
      float4 av = *reinterpret_cast<const float4*>(&As[k][ty * 4]);
      float4 bv = *reinterpret_cast<const float4*>(&Bs[k][tx * 4]);
      float am[4] = {av.x, av.y, av.z, av.w};
      float bn[4] = {bv.x, bv.y, bv.z, bv.w};
#pragma unroll
      for (int i = 0; i < 4; ++i)
#pragma unroll
        for (int j = 0; j < 4; ++j) acc[i][j] = fmaf(am[i], bn[j], acc[i][j]);
    }
  }
#pragma unroll
  for (int i = 0; i < 4; ++i) {
    float4 o = make_float4(acc[i][0], acc[i][1], acc[i][2], acc[i][3]);
    *reinterpret_cast<float4*>(wx + (size_t)(m0 + ty * 4 + i) * HDIM + n0 +
                               tx * 4) = o;
  }
}

extern "C" void kernel_launch(void* const* d_in, const int* in_sizes, int n_in,
                              void* d_out, int out_size, void* d_ws,
                              size_t ws_size, hipStream_t stream) {
  const float* x = (const float*)d_in[0];      // [32,1000,256]
  const float* W = (const float*)d_in[1];      // [512,256]
  const float* V = (const float*)d_in[2];      // [512,512]
  const float* alpha = (const float*)d_in[3];  // [512]
  const float* vthr = (const float*)d_in[4];   // [512]
  float* out = (float*)d_out;                  // [32,1000,512]

  const size_t wx_b = (size_t)BATCH * TSTEPS * HDIM * 4;  // 65,536,000
  const size_t xh_b = (size_t)BATCH * TSTEPS * KDIM * 2;  // 16,384,000
  const size_t wh_b = (size_t)HDIM * KDIM * 2;            //    262,144
  const size_t needA = wx_b + 2 * xh_b + 2 * wh_b + 128;  // ~98.8 MB
  const size_t needB = wx_b + 128;

  char* ws = (char*)d_ws;
  if (ws_size >= needA) {
    float* wx = (float*)ws;
    unsigned short* xh = (unsigned short*)(ws + wx_b);
    unsigned short* xl = xh + (size_t)BATCH * TSTEPS * KDIM;
    unsigned short* wh = (unsigned short*)(ws + wx_b + 2 * xh_b);
    unsigned short* wl = wh + (size_t)HDIM * KDIM;
    int* fs = (int*)(ws + wx_b + 2 * xh_b + 2 * wh_b);

    hipLaunchKernelGGL(init_fs, dim3(1), dim3(64), 0, stream, fs);
    hipLaunchKernelGGL(cast_split, dim3(8000), dim3(256), 0, stream, x, xh, xl,
                       BATCH * TSTEPS * KDIM / 4);
    hipLaunchKernelGGL(cast_split, dim3(128), dim3(256), 0, stream, W, wh, wl,
                       HDIM * KDIM / 4);
    hipLaunchKernelGGL(gemm_mfma, dim3(BATCH * TSTEPS / 128), dim3(256), 0,
                       stream, xh, xl, wh, wl, wx);
    hipLaunchKernelGGL(phase1, dim3(BATCH * 8), dim3(64), 0, stream, wx, alpha,
                       vthr, out, fs);
    hipLaunchKernelGGL(fallback_scan, dim3(BATCH), dim3(64), 0, stream, wx, V,
                       alpha, vthr, out, fs);
  } else if (ws_size >= needB) {
    float* wx = (float*)ws;
    int* fs = (int*)(ws + wx_b);
    hipLaunchKernelGGL(init_fs, dim3(1), dim3(64), 0, stream, fs);
    hipLaunchKernelGGL(gemm_xwT, dim3(BATCH * TSTEPS / 64, HDIM / 64),
                       dim3(256), 0, stream, x, W, wx);
    hipLaunchKernelGGL(phase1, dim3(BATCH * 8), dim3(64), 0, stream, wx, alpha,
                       vthr, out, fs);
    hipLaunchKernelGGL(fallback_scan, dim3(BATCH), dim3(64), 0, stream, wx, V,
                       alpha, vthr, out, fs);
  } else {
    float* wx = (ws_size >= wx_b) ? (float*)ws : out;
    hipLaunchKernelGGL(gemm_xwT, dim3(BATCH * TSTEPS / 64, HDIM / 64),
                       dim3(256), 0, stream, x, W, wx);
    hipLaunchKernelGGL(rlif_scan, dim3(BATCH), dim3(64), 0, stream, wx, V,
                       alpha, vthr, out);
  }
}

// Round 5
// 148.335 us; speedup vs baseline: 2.0333x; 1.2460x over previous
//
#include <hip/hip_runtime.h>

// Problem constants (from reference setup_inputs): B=32, T=1000, I=256, H=512
#define BATCH 32
#define TSTEPS 1000
#define KDIM 256
#define HDIM 512
#define PFD 50  // prefetch depth; TSTEPS % PFD == 0 (REQUIRED: unrolled tail)

#define ALPHA_MIN_F 0.8187307530779818f
#define ALPHA_MAX_F 0.9607894391523232f

typedef __attribute__((ext_vector_type(8))) short bf16x8;          // 8 bf16
typedef __attribute__((ext_vector_type(8))) unsigned short u16x8;  // 16B store
typedef __attribute__((ext_vector_type(4))) float f32x4;

static __device__ __forceinline__ unsigned short f2bf(float f) {
  unsigned u = __float_as_uint(f);
  u += 0x7FFF + ((u >> 16) & 1);  // round-to-nearest-even
  return (unsigned short)(u >> 16);
}
static __device__ __forceinline__ float bf2f(unsigned short s) {
  return __uint_as_float(((unsigned)s) << 16);
}

__global__ void init_fs(int* fs) {
  if (threadIdx.x < BATCH) fs[threadIdx.x] = TSTEPS;
}

// ---------------------------------------------------------------------------
// Split-cast + fragment pack: src f32 [R][256] -> hi/lo bf16 in MFMA
// fragment-major order: packed[((tile*8 + ks)*64 + lane)*8 + e] where the
// element is src[tile*16 + (lane&15)][(lane>>4)*8 + ks*32 + e]. This is a
// pure relocation of the round-4-PROVEN fragment map, so gemm reads identical
// values at coalesced addresses (1KB per wave per load). One block = 4 tiles.
// ---------------------------------------------------------------------------
__global__ __launch_bounds__(256) void cast_pack(const float* __restrict__ src,
                                                 unsigned short* __restrict__ hi,
                                                 unsigned short* __restrict__ lo,
                                                 int ntiles) {
  const int tile = blockIdx.x * 4 + (threadIdx.x >> 6);
  if (tile >= ntiles) return;
  const int lane = threadIdx.x & 63;
  const int row = tile * 16 + (lane & 15);
  const int kg = lane >> 4;
  const float* sp = src + (size_t)row * KDIM + kg * 8;
  unsigned short* hp = hi + (size_t)tile * 8 * 512 + lane * 8;
  unsigned short* lp = lo + (size_t)tile * 8 * 512 + lane * 8;
#pragma unroll
  for (int ks = 0; ks < 8; ++ks) {
    float4 a = *reinterpret_cast<const float4*>(sp + ks * 32);
    float4 b = *reinterpret_cast<const float4*>(sp + ks * 32 + 4);
    u16x8 h, l;
    h[0] = f2bf(a.x); l[0] = f2bf(a.x - bf2f(h[0]));
    h[1] = f2bf(a.y); l[1] = f2bf(a.y - bf2f(h[1]));
    h[2] = f2bf(a.z); l[2] = f2bf(a.z - bf2f(h[2]));
    h[3] = f2bf(a.w); l[3] = f2bf(a.w - bf2f(h[3]));
    h[4] = f2bf(b.x); l[4] = f2bf(b.x - bf2f(h[4]));
    h[5] = f2bf(b.y); l[5] = f2bf(b.y - bf2f(h[5]));
    h[6] = f2bf(b.z); l[6] = f2bf(b.z - bf2f(h[6]));
    h[7] = f2bf(b.w); l[7] = f2bf(b.w - bf2f(h[7]));
    *reinterpret_cast<u16x8*>(hp + ks * 512) = h;
    *reinterpret_cast<u16x8*>(lp + ks * 512) = l;
  }
}

// ---------------------------------------------------------------------------
// MFMA GEMM on packed fragments: wx[m][n] = sum_k x[m][k]*W[n][k], 3-pass
// bf16 split (hh+lh+hl). All fragment loads are coalesced 1KB dwordx4.
// 2000 waves (32 rows x 256 cols each) -> ~8 waves/CU for latency hiding.
// C/D mapping (m89-verified): col=lane&15, row=4*(lane>>4)+reg.
// ---------------------------------------------------------------------------
__global__ __launch_bounds__(256) void gemm_mfma(
    const unsigned short* __restrict__ xph, const unsigned short* __restrict__ xpl,
    const unsigned short* __restrict__ wph, const unsigned short* __restrict__ wpl,
    float* __restrict__ wx) {
  const int lane = threadIdx.x & 63;
  const int wid = threadIdx.x >> 6;
  const int tm = blockIdx.x * 4 + (wid & 1) * 2;  // first of 2 m-tiles
  const int nh = wid >> 1;                        // n-half: cols [nh*256, +256)
  const int row = lane & 15;
  const int kg = lane >> 4;
  const int m0 = tm * 16;

  // A fragments: 2 m-tiles x 8 k-steps, hi & lo (register-resident, reused x16)
  bf16x8 ah[2][8], al[2][8];
#pragma unroll
  for (int rt = 0; rt < 2; ++rt) {
#pragma unroll
    for (int ks = 0; ks < 8; ++ks) {
      const size_t off = ((size_t)(tm + rt) * 8 + ks) * 512 + lane * 8;
      ah[rt][ks] = *reinterpret_cast<const bf16x8*>(xph + off);
      al[rt][ks] = *reinterpret_cast<const bf16x8*>(xpl + off);
    }
  }

  for (int ct = 0; ct < 16; ++ct) {
    const int tile = nh * 16 + ct;
    const int n0 = tile * 16;
    f32x4 acc0 = {0.f, 0.f, 0.f, 0.f};
    f32x4 acc1 = {0.f, 0.f, 0.f, 0.f};
#pragma unroll
    for (int ks = 0; ks < 8; ++ks) {
      const size_t off = ((size_t)tile * 8 + ks) * 512 + lane * 8;
      bf16x8 bh = *reinterpret_cast<const bf16x8*>(wph + off);
      bf16x8 bl = *reinterpret_cast<const bf16x8*>(wpl + off);
      acc0 = __builtin_amdgcn_mfma_f32_16x16x32_bf16(ah[0][ks], bh, acc0, 0, 0, 0);
      acc1 = __builtin_amdgcn_mfma_f32_16x16x32_bf16(ah[1][ks], bh, acc1, 0, 0, 0);
      acc0 = __builtin_amdgcn_mfma_f32_16x16x32_bf16(al[0][ks], bh, acc0, 0, 0, 0);
      acc1 = __builtin_amdgcn_mfma_f32_16x16x32_bf16(al[1][ks], bh, acc1, 0, 0, 0);
      acc0 = __builtin_amdgcn_mfma_f32_16x16x32_bf16(ah[0][ks], bl, acc0, 0, 0, 0);
      acc1 = __builtin_amdgcn_mfma_f32_16x16x32_bf16(ah[1][ks], bl, acc1, 0, 0, 0);
    }
#pragma unroll
    for (int j = 0; j < 4; ++j) {
      wx[(size_t)(m0 + kg * 4 + j) * HDIM + n0 + row] = acc0[j];
      wx[(size_t)(m0 + 16 + kg * 4 + j) * HDIM + n0 + row] = acc1[j];
    }
  }
}

// ---------------------------------------------------------------------------
// Phase 1 (round-3/4-proven structure): per-channel uncoupled scan (r=0).
// One thread per (b,h); exact up to and including the batch's first true
// spike; records it via atomicMin. PFD=50 (1000 % 50 == 0 REQUIRED - the
// round-2 failure was PFD=16 writing OOB; 50 outstanding loads < vmcnt cap).
// ---------------------------------------------------------------------------
__global__ __launch_bounds__(64) void phase1(const float* __restrict__ wx,
                                             const float* __restrict__ alpha,
                                             const float* __restrict__ vthr,
                                             float* __restrict__ out,
                                             int* __restrict__ fs) {
  const int b = blockIdx.x >> 3;
  const int h = ((blockIdx.x & 7) << 6) + threadIdx.x;
  const float a = fminf(fmaxf(alpha[h], ALPHA_MIN_F), ALPHA_MAX_F);
  const float na = 1.0f - a;
  const float th = vthr[h];
  const float* wp = wx + (size_t)b * TSTEPS * HDIM + h;
  float* op = out + (size_t)b * TSTEPS * HDIM + h;

  float u = 0.f, s = 0.f;
  int first = TSTEPS;

  float pf[PFD];
#pragma unroll
  for (int d = 0; d < PFD; ++d) pf[d] = wp[(size_t)d * HDIM];

  for (int t0 = 0; t0 < TSTEPS; t0 += PFD) {
#pragma unroll
    for (int ts = 0; ts < PFD; ++ts) {
      const int t = t0 + ts;
      const float w = pf[ts];
      int tp = t + PFD;
      if (tp > TSTEPS - 1) tp = TSTEPS - 1;  // clamped harmless tail reload
      pf[ts] = wp[(size_t)tp * HDIM];
      u = fmaf(a, u - s, na * w);
      s = (u > th) ? 1.0f : 0.0f;
      op[(size_t)t * HDIM] = s;
      if (s != 0.0f && first == TSTEPS) {
        first = t;
        atomicMin(&fs[b], t);
      }
    }
  }
}

// ---------------------------------------------------------------------------
// Full coupled scan body (round-1-proven): one wave per batch, sparse s@Vz
// via ballot. Used gated (fallback) and ungated (tiny-ws tier).
// ---------------------------------------------------------------------------
static __device__ __forceinline__ void scan_body(const float* wxbuf,
                                                 const float* __restrict__ V,
                                                 const float* __restrict__ alpha,
                                                 const float* __restrict__ vthr,
                                                 float* out, int b) {
  const int l = threadIdx.x;
  const int h0 = 4 * l;
  const int h1 = 256 + 4 * l;

  float4 al0 = *reinterpret_cast<const float4*>(alpha + h0);
  float4 al1 = *reinterpret_cast<const float4*>(alpha + h1);
  float4 th0 = *reinterpret_cast<const float4*>(vthr + h0);
  float4 th1 = *reinterpret_cast<const float4*>(vthr + h1);
  float a[8] = {al0.x, al0.y, al0.z, al0.w, al1.x, al1.y, al1.z, al1.w};
  float th[8] = {th0.x, th0.y, th0.z, th0.w, th1.x, th1.y, th1.z, th1.w};
  float na[8], u[8], s[8], r[8];
#pragma unroll
  for (int j = 0; j < 8; ++j) {
    float c = fminf(fmaxf(a[j], ALPHA_MIN_F), ALPHA_MAX_F);
    a[j] = c; na[j] = 1.0f - c;
    u[j] = 0.f; s[j] = 0.f; r[j] = 0.f;
  }
  const float* wb = wxbuf + (size_t)b * TSTEPS * HDIM;
  float* ob = out + (size_t)b * TSTEPS * HDIM;
  float4 p0[4], p1[4];
#pragma unroll
  for (int d = 0; d < 4; ++d) {
    p0[d] = *reinterpret_cast<const float4*>(wb + (size_t)d * HDIM + h0);
    p1[d] = *reinterpret_cast<const float4*>(wb + (size_t)d * HDIM + h1);
  }
  for (int t0 = 0; t0 < TSTEPS; t0 += 4) {
#pragma unroll
    for (int ts = 0; ts < 4; ++ts) {
      const int t = t0 + ts;
      float w8[8] = {p0[ts].x, p0[ts].y, p0[ts].z, p0[ts].w,
                     p1[ts].x, p1[ts].y, p1[ts].z, p1[ts].w};
      int tpre = t + 4;
      if (tpre > TSTEPS - 1) tpre = TSTEPS - 1;
      p0[ts] = *reinterpret_cast<const float4*>(wb + (size_t)tpre * HDIM + h0);
      p1[ts] = *reinterpret_cast<const float4*>(wb + (size_t)tpre * HDIM + h1);
#pragma unroll
      for (int j = 0; j < 8; ++j) {
        float un = fmaf(a[j], u[j] - s[j], na[j] * (w8[j] + r[j]));
        u[j] = un;
        s[j] = (un > th[j]) ? 1.0f : 0.0f;
      }
      *reinterpret_cast<float4*>(ob + (size_t)t * HDIM + h0) =
          make_float4(s[0], s[1], s[2], s[3]);
      *reinterpret_cast<float4*>(ob + (size_t)t * HDIM + h1) =
          make_float4(s[4], s[5], s[6], s[7]);
      float ssum = s[0] + s[1] + s[2] + s[3] + s[4] + s[5] + s[6] + s[7];
      unsigned long long anym = __ballot(ssum != 0.0f);
      if (anym != 0ull) {
        unsigned long long mk[8];
#pragma unroll
        for (int j = 0; j < 8; ++j) mk[j] = __ballot(s[j] != 0.0f);
        float rr[8] = {0.f, 0.f, 0.f, 0.f, 0.f, 0.f, 0.f, 0.f};
#pragma unroll
        for (int j2 = 0; j2 < 8; ++j2) {
          unsigned long long m = mk[j2];
          while (m) {  // wave-uniform (masks identical on all lanes)
            int src = __builtin_ctzll(m);
            m &= m - 1;
            int hin = (j2 < 4) ? (src * 4 + j2) : (256 + src * 4 + (j2 - 4));
            const float* vrow = V + (size_t)hin * HDIM;
            float4 v0 = *reinterpret_cast<const float4*>(vrow + h0);
            float4 v1 = *reinterpret_cast<const float4*>(vrow + h1);
            float vv[8] = {v0.x, v0.y, v0.z, v0.w, v1.x, v1.y, v1.z, v1.w};
#pragma unroll
            for (int j = 0; j < 8; ++j) {
              int hj = (j < 4) ? (h0 + j) : (h1 + j - 4);
              rr[j] += (hj == hin) ? 0.0f : vv[j];  // zeroed diagonal
            }
          }
        }
#pragma unroll
        for (int j = 0; j < 8; ++j) r[j] = rr[j];
      } else {
#pragma unroll
        for (int j = 0; j < 8; ++j) r[j] = 0.0f;
      }
    }
  }
}

// Gated fallback: only batches whose first spike is at t <= TSTEPS-2 need the
// coupled recompute (a spike at the last step cannot affect any output).
__global__ __launch_bounds__(64) void fallback_scan(
    const float* wxbuf, const float* __restrict__ V,
    const float* __restrict__ alpha, const float* __restrict__ vthr,
    float* out, const int* __restrict__ fs) {
  const int b = blockIdx.x;
  if (fs[b] >= TSTEPS - 1) return;
  scan_body(wxbuf, V, alpha, vthr, out, b);
}

// Ungated (tiny-ws tier, round-1 semantics).
__global__ __launch_bounds__(64) void rlif_scan(const float* wxbuf,
                                                const float* __restrict__ V,
                                                const float* __restrict__ alpha,
                                                const float* __restrict__ vthr,
                                                float* out) {
  scan_body(wxbuf, V, alpha, vthr, out, blockIdx.x);
}

// ---------------------------------------------------------------------------
// Tier-B f32 GEMM (round-1-proven).
// ---------------------------------------------------------------------------
__global__ __launch_bounds__(256) void gemm_xwT(const float* __restrict__ x,
                                                const float* __restrict__ W,
                                                float* __restrict__ wx) {
  __shared__ float As[32][64];
  __shared__ float Bs[32][64];
  const int m0 = blockIdx.x * 64;
  const int n0 = blockIdx.y * 64;
  const int tid = threadIdx.x;
  const int tx = tid & 15;
  const int ty = tid >> 4;
  const int lr = tid >> 2;
  const int lk = (tid & 3) * 8;

  float acc[4][4] = {};
  for (int k0 = 0; k0 < KDIM; k0 += 32) {
    const float4* ap =
        reinterpret_cast<const float4*>(x + (size_t)(m0 + lr) * KDIM + k0 + lk);
    const float4* bp =
        reinterpret_cast<const float4*>(W + (size_t)(n0 + lr) * KDIM + k0 + lk);
    float4 a0 = ap[0], a1 = ap[1];
    float4 b0 = bp[0], b1 = bp[1];
    __syncthreads();
    As[lk + 0][lr] = a0.x; As[lk + 1][lr] = a0.y;
    As[lk + 2][lr] = a0.z; As[lk + 3][lr] = a0.w;
    As[lk + 4][lr] = a1.x; As[lk + 5][lr] = a1.y;
    As[lk + 6][lr] = a1.z; As[lk + 7][lr] = a1.w;
    Bs[lk + 0][lr] = b0.x; Bs[lk + 1][lr] = b0.y;
    Bs[lk + 2][lr] = b0.z; Bs[lk + 3][lr] = b0.w;
    Bs[lk + 4][lr] = b1.x; Bs[lk + 5][lr] = b1.y;
    Bs[lk + 6][lr] = b1.z; Bs[lk + 7][lr] = b1.w;
    __syncthreads();
#pragma unroll
    for (int k = 0; k < 32; ++k) {
      float4 av = *reinterpret_cast<const float4*>(&As[k][ty * 4]);
      float4 bv = *reinterpret_cast<const float4*>(&Bs[k][tx * 4]);
      float am[4] = {av.x, av.y, av.z, av.w};
      float bn[4] = {bv.x, bv.y, bv.z, bv.w};
#pragma unroll
      for (int i = 0; i < 4; ++i)
#pragma unroll
        for (int j = 0; j < 4; ++j) acc[i][j] = fmaf(am[i], bn[j], acc[i][j]);
    }
  }
#pragma unroll
  for (int i = 0; i < 4; ++i) {
    float4 o = make_float4(acc[i][0], acc[i][1], acc[i][2], acc[i][3]);
    *reinterpret_cast<float4*>(wx + (size_t)(m0 + ty * 4 + i) * HDIM + n0 +
                               tx * 4) = o;
  }
}

extern "C" void kernel_launch(void* const* d_in, const int* in_sizes, int n_in,
                              void* d_out, int out_size, void* d_ws,
                              size_t ws_size, hipStream_t stream) {
  const float* x = (const float*)d_in[0];      // [32,1000,256]
  const float* W = (const float*)d_in[1];      // [512,256]
  const float* V = (const float*)d_in[2];      // [512,512]
  const float* alpha = (const float*)d_in[3];  // [512]
  const float* vthr = (const float*)d_in[4];   // [512]
  float* out = (float*)d_out;                  // [32,1000,512]

  const size_t wx_b = (size_t)BATCH * TSTEPS * HDIM * 4;  // 65,536,000
  const size_t xp_b = (size_t)BATCH * TSTEPS * KDIM * 2;  // 16,384,000
  const size_t wp_b = (size_t)HDIM * KDIM * 2;            //    262,144
  const size_t needA = wx_b + 2 * xp_b + 2 * wp_b + 128;  // ~98.8 MB
  const size_t needB = wx_b + 128;

  char* ws = (char*)d_ws;
  if (ws_size >= needA) {
    float* wx = (float*)ws;
    unsigned short* xph = (unsigned short*)(ws + wx_b);
    unsigned short* xpl = xph + (size_t)BATCH * TSTEPS * KDIM;
    unsigned short* wph = (unsigned short*)(ws + wx_b + 2 * xp_b);
    unsigned short* wpl = wph + (size_t)HDIM * KDIM;
    int* fs = (int*)(ws + wx_b + 2 * xp_b + 2 * wp_b);

    hipLaunchKernelGGL(init_fs, dim3(1), dim3(64), 0, stream, fs);
    // x: 2000 m-tiles -> 500 blocks; W: 32 n-tiles -> 8 blocks
    hipLaunchKernelGGL(cast_pack, dim3(500), dim3(256), 0, stream, x, xph, xpl,
                       BATCH * TSTEPS / 16);
    hipLaunchKernelGGL(cast_pack, dim3(8), dim3(256), 0, stream, W, wph, wpl,
                       HDIM / 16);
    hipLaunchKernelGGL(gemm_mfma, dim3(BATCH * TSTEPS / 64), dim3(256), 0,
                       stream, xph, xpl, wph, wpl, wx);
    hipLaunchKernelGGL(phase1, dim3(BATCH * 8), dim3(64), 0, stream, wx, alpha,
                       vthr, out, fs);
    hipLaunchKernelGGL(fallback_scan, dim3(BATCH), dim3(64), 0, stream, wx, V,
                       alpha, vthr, out, fs);
  } else if (ws_size >= needB) {
    float* wx = (float*)ws;
    int* fs = (int*)(ws + wx_b);
    hipLaunchKernelGGL(init_fs, dim3(1), dim3(64), 0, stream, fs);
    hipLaunchKernelGGL(gemm_xwT, dim3(BATCH * TSTEPS / 64, HDIM / 64),
                       dim3(256), 0, stream, x, W, wx);
    hipLaunchKernelGGL(phase1, dim3(BATCH * 8), dim3(64), 0, stream, wx, alpha,
                       vthr, out, fs);
    hipLaunchKernelGGL(fallback_scan, dim3(BATCH), dim3(64), 0, stream, wx, V,
                       alpha, vthr, out, fs);
  } else {
    float* wx = (ws_size >= wx_b) ? (float*)ws : out;
    hipLaunchKernelGGL(gemm_xwT, dim3(BATCH * TSTEPS / 64, HDIM / 64),
                       dim3(256), 0, stream, x, W, wx);
    hipLaunchKernelGGL(rlif_scan, dim3(BATCH), dim3(64), 0, stream, wx, V,
                       alpha, vthr, out);
  }
}

// Round 6
// 84.350 us; speedup vs baseline: 3.5758x; 1.7586x over previous
//
#include <hip/hip_runtime.h>

// Problem constants (from reference setup_inputs): B=32, T=1000, I=256, H=512
#define BATCH 32
#define TSTEPS 1000
#define KDIM 256
#define HDIM 512
#define NSEG 8    // T-segments for the parallel scan
#define SEGL 125  // TSTEPS / NSEG
#define SPFD 25   // prefetch depth; SEGL % SPFD == 0 (REQUIRED: unrolled tail)

#define ALPHA_MIN_F 0.8187307530779818f
#define ALPHA_MAX_F 0.9607894391523232f

typedef __attribute__((ext_vector_type(8))) short bf16x8;          // 8 bf16
typedef __attribute__((ext_vector_type(8))) unsigned short u16x8;  // 16B store
typedef __attribute__((ext_vector_type(4))) float f32x4;

static __device__ __forceinline__ unsigned short f2bf(float f) {
  unsigned u = __float_as_uint(f);
  u += 0x7FFF + ((u >> 16) & 1);  // round-to-nearest-even
  return (unsigned short)(u >> 16);
}
static __device__ __forceinline__ float bf2f(unsigned short s) {
  return __uint_as_float(((unsigned)s) << 16);
}

__global__ void init_fs(int* fs) {
  if (threadIdx.x < BATCH) fs[threadIdx.x] = TSTEPS;
}

// ---------------------------------------------------------------------------
// Split-cast + fragment pack (round-5-proven; now used for W only):
// packed[((tile*8+ks)*64+lane)*8+e] = src[tile*16+(lane&15)][(lane>>4)*8+ks*32+e]
// ---------------------------------------------------------------------------
__global__ __launch_bounds__(256) void cast_pack(const float* __restrict__ src,
                                                 unsigned short* __restrict__ hi,
                                                 unsigned short* __restrict__ lo,
                                                 int ntiles) {
  const int tile = blockIdx.x * 4 + (threadIdx.x >> 6);
  if (tile >= ntiles) return;
  const int lane = threadIdx.x & 63;
  const int row = tile * 16 + (lane & 15);
  const int kg = lane >> 4;
  const float* sp = src + (size_t)row * KDIM + kg * 8;
  unsigned short* hp = hi + (size_t)tile * 8 * 512 + lane * 8;
  unsigned short* lp = lo + (size_t)tile * 8 * 512 + lane * 8;
#pragma unroll
  for (int ks = 0; ks < 8; ++ks) {
    float4 a = *reinterpret_cast<const float4*>(sp + ks * 32);
    float4 b = *reinterpret_cast<const float4*>(sp + ks * 32 + 4);
    u16x8 h, l;
    h[0] = f2bf(a.x); l[0] = f2bf(a.x - bf2f(h[0]));
    h[1] = f2bf(a.y); l[1] = f2bf(a.y - bf2f(h[1]));
    h[2] = f2bf(a.z); l[2] = f2bf(a.z - bf2f(h[2]));
    h[3] = f2bf(a.w); l[3] = f2bf(a.w - bf2f(h[3]));
    h[4] = f2bf(b.x); l[4] = f2bf(b.x - bf2f(h[4]));
    h[5] = f2bf(b.y); l[5] = f2bf(b.y - bf2f(h[5]));
    h[6] = f2bf(b.z); l[6] = f2bf(b.z - bf2f(h[6]));
    h[7] = f2bf(b.w); l[7] = f2bf(b.w - bf2f(h[7]));
    *reinterpret_cast<u16x8*>(hp + ks * 512) = h;
    *reinterpret_cast<u16x8*>(lp + ks * 512) = l;
  }
}

// ---------------------------------------------------------------------------
// MFMA GEMM: wx[m][n] = sum_k x[m][k]*W[n][k], 3-pass bf16 split (hh+lh+hl).
// A: loaded directly from f32 x and split in-registers (read once, reused x32;
//    same k-map as the proven packed layout: k = (lane>>4)*8 + ks*32 + e).
// B: packed W staged per n-tile into LDS (double-buffered, issue-early /
//    write-late), shared by all 4 waves -> B L2 traffic 512MB -> 128MB.
// Block = 4 waves x 2 m-tiles = 128 rows; each wave covers all 512 cols.
// C/D mapping (m89-verified): col=lane&15, row=4*(lane>>4)+reg.
// ---------------------------------------------------------------------------
__global__ __launch_bounds__(256, 1) void gemm_mfma(
    const float* __restrict__ x, const unsigned short* __restrict__ wph,
    const unsigned short* __restrict__ wpl, float* __restrict__ wx) {
  __shared__ short bsh[2][2][4096];  // [buf][hi/lo][ks*512 + lane*8 + e], 32KB
  const int tid = threadIdx.x;
  const int lane = tid & 63;
  const int wid = tid >> 6;
  const int row = lane & 15;
  const int kg = lane >> 4;
  const int tmb = blockIdx.x * 8 + wid * 2;  // first of this wave's 2 m-tiles
  const int m0 = tmb * 16;
  const int tO = tid * 8;  // staging offset in shorts (0..2040)

  // A fragments: 2 m-tiles x 8 ks, hi & lo, split from f32 in-registers.
  bf16x8 ah[2][8], al[2][8];
#pragma unroll
  for (int rt = 0; rt < 2; ++rt) {
    const float* xp = x + (size_t)((tmb + rt) * 16 + row) * KDIM + kg * 8;
#pragma unroll
    for (int ks = 0; ks < 8; ++ks) {
      float4 f0 = *reinterpret_cast<const float4*>(xp + ks * 32);
      float4 f1 = *reinterpret_cast<const float4*>(xp + ks * 32 + 4);
      bf16x8 hv, lv;
      hv[0] = (short)f2bf(f0.x); lv[0] = (short)f2bf(f0.x - bf2f(hv[0]));
      hv[1] = (short)f2bf(f0.y); lv[1] = (short)f2bf(f0.y - bf2f(hv[1]));
      hv[2] = (short)f2bf(f0.z); lv[2] = (short)f2bf(f0.z - bf2f(hv[2]));
      hv[3] = (short)f2bf(f0.w); lv[3] = (short)f2bf(f0.w - bf2f(hv[3]));
      hv[4] = (short)f2bf(f1.x); lv[4] = (short)f2bf(f1.x - bf2f(hv[4]));
      hv[5] = (short)f2bf(f1.y); lv[5] = (short)f2bf(f1.y - bf2f(hv[5]));
      hv[6] = (short)f2bf(f1.z); lv[6] = (short)f2bf(f1.z - bf2f(hv[6]));
      hv[7] = (short)f2bf(f1.w); lv[7] = (short)f2bf(f1.w - bf2f(hv[7]));
      ah[rt][ks] = hv;
      al[rt][ks] = lv;
    }
  }

  // Prologue: stage n-tile 0 into buf 0.
  {
    *reinterpret_cast<bf16x8*>(&bsh[0][0][tO]) =
        *reinterpret_cast<const bf16x8*>(wph + tO);
    *reinterpret_cast<bf16x8*>(&bsh[0][0][2048 + tO]) =
        *reinterpret_cast<const bf16x8*>(wph + 2048 + tO);
    *reinterpret_cast<bf16x8*>(&bsh[0][1][tO]) =
        *reinterpret_cast<const bf16x8*>(wpl + tO);
    *reinterpret_cast<bf16x8*>(&bsh[0][1][2048 + tO]) =
        *reinterpret_cast<const bf16x8*>(wpl + 2048 + tO);
  }
  __syncthreads();

  for (int ct = 0; ct < 32; ++ct) {
    const int buf = ct & 1;
    // Issue next tile's global loads early (latency hidden under MFMAs).
    bf16x8 nh0, nh1, nl0, nl1;
    const bool pre = (ct < 31);
    if (pre) {
      const unsigned short* sh = wph + (size_t)(ct + 1) * 4096;
      const unsigned short* sl = wpl + (size_t)(ct + 1) * 4096;
      nh0 = *reinterpret_cast<const bf16x8*>(sh + tO);
      nh1 = *reinterpret_cast<const bf16x8*>(sh + 2048 + tO);
      nl0 = *reinterpret_cast<const bf16x8*>(sl + tO);
      nl1 = *reinterpret_cast<const bf16x8*>(sl + 2048 + tO);
    }

    f32x4 acc0 = {0.f, 0.f, 0.f, 0.f};
    f32x4 acc1 = {0.f, 0.f, 0.f, 0.f};
#pragma unroll
    for (int ks = 0; ks < 8; ++ks) {
      bf16x8 bh = *reinterpret_cast<const bf16x8*>(&bsh[buf][0][ks * 512 + lane * 8]);
      bf16x8 bl = *reinterpret_cast<const bf16x8*>(&bsh[buf][1][ks * 512 + lane * 8]);
      acc0 = __builtin_amdgcn_mfma_f32_16x16x32_bf16(ah[0][ks], bh, acc0, 0, 0, 0);
      acc1 = __builtin_amdgcn_mfma_f32_16x16x32_bf16(ah[1][ks], bh, acc1, 0, 0, 0);
      acc0 = __builtin_amdgcn_mfma_f32_16x16x32_bf16(al[0][ks], bh, acc0, 0, 0, 0);
      acc1 = __builtin_amdgcn_mfma_f32_16x16x32_bf16(al[1][ks], bh, acc1, 0, 0, 0);
      acc0 = __builtin_amdgcn_mfma_f32_16x16x32_bf16(ah[0][ks], bl, acc0, 0, 0, 0);
      acc1 = __builtin_amdgcn_mfma_f32_16x16x32_bf16(ah[1][ks], bl, acc1, 0, 0, 0);
    }
    const int n0 = ct * 16;
#pragma unroll
    for (int j = 0; j < 4; ++j) {
      wx[(size_t)(m0 + kg * 4 + j) * HDIM + n0 + row] = acc0[j];
      wx[(size_t)(m0 + 16 + kg * 4 + j) * HDIM + n0 + row] = acc1[j];
    }
    if (pre) {  // write-late into the other buffer
      *reinterpret_cast<bf16x8*>(&bsh[buf ^ 1][0][tO]) = nh0;
      *reinterpret_cast<bf16x8*>(&bsh[buf ^ 1][0][2048 + tO]) = nh1;
      *reinterpret_cast<bf16x8*>(&bsh[buf ^ 1][1][tO]) = nl0;
      *reinterpret_cast<bf16x8*>(&bsh[buf ^ 1][1][2048 + tO]) = nl1;
    }
    __syncthreads();
  }
}

// ---------------------------------------------------------------------------
// Pass A: per-(b,seg,h) particular solution of the LINEAR recurrence over the
// segment: c = sum_j a^(SEGL-1-j) * na * w_j, computed by the same iteration
// c = fma(a, c, na*w). 2048 waves -> BW-bound.
// ---------------------------------------------------------------------------
__global__ __launch_bounds__(64) void seg_sum(const float* __restrict__ wx,
                                              const float* __restrict__ alpha,
                                              float* __restrict__ cbuf) {
  const int hb = blockIdx.x & 7;
  const int seg = (blockIdx.x >> 3) & 7;
  const int b = blockIdx.x >> 6;
  const int h = (hb << 6) + threadIdx.x;
  const float a = fminf(fmaxf(alpha[h], ALPHA_MIN_F), ALPHA_MAX_F);
  const float na = 1.0f - a;
  const float* wp = wx + ((size_t)b * TSTEPS + seg * SEGL) * HDIM + h;

  float pf[SPFD];
#pragma unroll
  for (int d = 0; d < SPFD; ++d) pf[d] = wp[(size_t)d * HDIM];

  float c = 0.f;
  for (int j0 = 0; j0 < SEGL; j0 += SPFD) {
#pragma unroll
    for (int js = 0; js < SPFD; ++js) {
      const int j = j0 + js;
      const float w = pf[js];
      int jp = j + SPFD;
      if (jp > SEGL - 1) jp = SEGL - 1;  // clamped in-segment tail reload
      pf[js] = wp[(size_t)jp * HDIM];
      c = fmaf(a, c, na * w);
    }
  }
  cbuf[(size_t)seg * BATCH * HDIM + (size_t)b * HDIM + h] = c;
}

// ---------------------------------------------------------------------------
// Pass B: reconstruct the linear boundary state u_start = fold_k fma(a^SEGL,
// u, c_k), then run the NONLINEAR per-channel dynamics (self-reset, r=0) for
// the segment. Exact (to ulp) up to the batch's first true spike t*: before
// t* the true dynamics are linear, so every segment start below/at t* is
// right, t* is detected exactly via atomicMin, and spurious later spikes
// cannot lower the min. Spiking batches are rewritten by fallback_scan.
// ---------------------------------------------------------------------------
__global__ __launch_bounds__(64) void seg_scan(const float* __restrict__ wx,
                                               const float* __restrict__ alpha,
                                               const float* __restrict__ vthr,
                                               const float* __restrict__ cbuf,
                                               float* __restrict__ out,
                                               int* __restrict__ fs) {
  const int hb = blockIdx.x & 7;
  const int seg = (blockIdx.x >> 3) & 7;
  const int b = blockIdx.x >> 6;
  const int h = (hb << 6) + threadIdx.x;
  const float a = fminf(fmaxf(alpha[h], ALPHA_MIN_F), ALPHA_MAX_F);
  const float na = 1.0f - a;
  const float th = vthr[h];
  const int t0g = seg * SEGL;
  const float* wp = wx + ((size_t)b * TSTEPS + t0g) * HDIM + h;
  float* op = out + ((size_t)b * TSTEPS + t0g) * HDIM + h;

  // Issue the prefetch pipeline first so it overlaps the u_start computation.
  float pf[SPFD];
#pragma unroll
  for (int d = 0; d < SPFD; ++d) pf[d] = wp[(size_t)d * HDIM];

  // a^SEGL (serial mults; ~ulp-accurate on a tiny factor, error << threshold)
  float aL = 1.0f;
  for (int i = 0; i < SEGL; ++i) aL *= a;
  float u = 0.f;
  for (int k = 0; k < seg; ++k)  // wave-uniform bound (seg is block-wide)
    u = fmaf(aL, u, cbuf[(size_t)k * BATCH * HDIM + (size_t)b * HDIM + h]);

  float s = 0.f;
  int first = TSTEPS;
  for (int j0 = 0; j0 < SEGL; j0 += SPFD) {
#pragma unroll
    for (int js = 0; js < SPFD; ++js) {
      const int j = j0 + js;
      const float w = pf[js];
      int jp = j + SPFD;
      if (jp > SEGL - 1) jp = SEGL - 1;  // clamped in-segment tail reload
      pf[js] = wp[(size_t)jp * HDIM];
      u = fmaf(a, u - s, na * w);
      s = (u > th) ? 1.0f : 0.0f;
      op[(size_t)j * HDIM] = s;
      if (s != 0.0f && first == TSTEPS) {
        first = t0g + j;
        atomicMin(&fs[b], first);
      }
    }
  }
}

// ---------------------------------------------------------------------------
// Full coupled scan body (round-1-proven): one wave per batch, sparse s@Vz
// via ballot. Used gated (fallback) and ungated (tiny-ws tier).
// ---------------------------------------------------------------------------
static __device__ __forceinline__ void scan_body(const float* wxbuf,
                                                 const float* __restrict__ V,
                                                 const float* __restrict__ alpha,
                                                 const float* __restrict__ vthr,
                                                 float* out, int b) {
  const int l = threadIdx.x;
  const int h0 = 4 * l;
  const int h1 = 256 + 4 * l;

  float4 al0 = *reinterpret_cast<const float4*>(alpha + h0);
  float4 al1 = *reinterpret_cast<const float4*>(alpha + h1);
  float4 th0 = *reinterpret_cast<const float4*>(vthr + h0);
  float4 th1 = *reinterpret_cast<const float4*>(vthr + h1);
  float a[8] = {al0.x, al0.y, al0.z, al0.w, al1.x, al1.y, al1.z, al1.w};
  float th[8] = {th0.x, th0.y, th0.z, th0.w, th1.x, th1.y, th1.z, th1.w};
  float na[8], u[8], s[8], r[8];
#pragma unroll
  for (int j = 0; j < 8; ++j) {
    float c = fminf(fmaxf(a[j], ALPHA_MIN_F), ALPHA_MAX_F);
    a[j] = c; na[j] = 1.0f - c;
    u[j] = 0.f; s[j] = 0.f; r[j] = 0.f;
  }
  const float* wb = wxbuf + (size_t)b * TSTEPS * HDIM;
  float* ob = out + (size_t)b * TSTEPS * HDIM;
  float4 p0[4], p1[4];
#pragma unroll
  for (int d = 0; d < 4; ++d) {
    p0[d] = *reinterpret_cast<const float4*>(wb + (size_t)d * HDIM + h0);
    p1[d] = *reinterpret_cast<const float4*>(wb + (size_t)d * HDIM + h1);
  }
  for (int t0 = 0; t0 < TSTEPS; t0 += 4) {
#pragma unroll
    for (int ts = 0; ts < 4; ++ts) {
      const int t = t0 + ts;
      float w8[8] = {p0[ts].x, p0[ts].y, p0[ts].z, p0[ts].w,
                     p1[ts].x, p1[ts].y, p1[ts].z, p1[ts].w};
      int tpre = t + 4;
      if (tpre > TSTEPS - 1) tpre = TSTEPS - 1;
      p0[ts] = *reinterpret_cast<const float4*>(wb + (size_t)tpre * HDIM + h0);
      p1[ts] = *reinterpret_cast<const float4*>(wb + (size_t)tpre * HDIM + h1);
#pragma unroll
      for (int j = 0; j < 8; ++j) {
        float un = fmaf(a[j], u[j] - s[j], na[j] * (w8[j] + r[j]));
        u[j] = un;
        s[j] = (un > th[j]) ? 1.0f : 0.0f;
      }
      *reinterpret_cast<float4*>(ob + (size_t)t * HDIM + h0) =
          make_float4(s[0], s[1], s[2], s[3]);
      *reinterpret_cast<float4*>(ob + (size_t)t * HDIM + h1) =
          make_float4(s[4], s[5], s[6], s[7]);
      float ssum = s[0] + s[1] + s[2] + s[3] + s[4] + s[5] + s[6] + s[7];
      unsigned long long anym = __ballot(ssum != 0.0f);
      if (anym != 0ull) {
        unsigned long long mk[8];
#pragma unroll
        for (int j = 0; j < 8; ++j) mk[j] = __ballot(s[j] != 0.0f);
        float rr[8] = {0.f, 0.f, 0.f, 0.f, 0.f, 0.f, 0.f, 0.f};
#pragma unroll
        for (int j2 = 0; j2 < 8; ++j2) {
          unsigned long long m = mk[j2];
          while (m) {  // wave-uniform (masks identical on all lanes)
            int src = __builtin_ctzll(m);
            m &= m - 1;
            int hin = (j2 < 4) ? (src * 4 + j2) : (256 + src * 4 + (j2 - 4));
            const float* vrow = V + (size_t)hin * HDIM;
            float4 v0 = *reinterpret_cast<const float4*>(vrow + h0);
            float4 v1 = *reinterpret_cast<const float4*>(vrow + h1);
            float vv[8] = {v0.x, v0.y, v0.z, v0.w, v1.x, v1.y, v1.z, v1.w};
#pragma unroll
            for (int j = 0; j < 8; ++j) {
              int hj = (j < 4) ? (h0 + j) : (h1 + j - 4);
              rr[j] += (hj == hin) ? 0.0f : vv[j];  // zeroed diagonal
            }
          }
        }
#pragma unroll
        for (int j = 0; j < 8; ++j) r[j] = rr[j];
      } else {
#pragma unroll
        for (int j = 0; j < 8; ++j) r[j] = 0.0f;
      }
    }
  }
}

// Gated fallback: only batches whose first spike is at t <= TSTEPS-2 need the
// coupled recompute (a spike at the last step cannot affect any output).
__global__ __launch_bounds__(64) void fallback_scan(
    const float* wxbuf, const float* __restrict__ V,
    const float* __restrict__ alpha, const float* __restrict__ vthr,
    float* out, const int* __restrict__ fs) {
  const int b = blockIdx.x;
  if (fs[b] >= TSTEPS - 1) return;
  scan_body(wxbuf, V, alpha, vthr, out, b);
}

// Ungated (tiny-ws tier, round-1 semantics).
__global__ __launch_bounds__(64) void rlif_scan(const float* wxbuf,
                                                const float* __restrict__ V,
                                                const float* __restrict__ alpha,
                                                const float* __restrict__ vthr,
                                                float* out) {
  scan_body(wxbuf, V, alpha, vthr, out, blockIdx.x);
}

// ---------------------------------------------------------------------------
// Tier-B f32 GEMM (round-1-proven).
// ---------------------------------------------------------------------------
__global__ __launch_bounds__(256) void gemm_xwT(const float* __restrict__ x,
                                                const float* __restrict__ W,
                                                float* __restrict__ wx) {
  __shared__ float As[32][64];
  __shared__ float Bs[32][64];
  const int m0 = blockIdx.x * 64;
  const int n0 = blockIdx.y * 64;
  const int tid = threadIdx.x;
  const int tx = tid & 15;
  const int ty = tid >> 4;
  const int lr = tid >> 2;
  const int lk = (tid & 3) * 8;

  float acc[4][4] = {};
  for (int k0 = 0; k0 < KDIM; k0 += 32) {
    const float4* ap =
        reinterpret_cast<const float4*>(x + (size_t)(m0 + lr) * KDIM + k0 + lk);
    const float4* bp =
        reinterpret_cast<const float4*>(W + (size_t)(n0 + lr) * KDIM + k0 + lk);
    float4 a0 = ap[0], a1 = ap[1];
    float4 b0 = bp[0], b1 = bp[1];
    __syncthreads();
    As[lk + 0][lr] = a0.x; As[lk + 1][lr] = a0.y;
    As[lk + 2][lr] = a0.z; As[lk + 3][lr] = a0.w;
    As[lk + 4][lr] = a1.x; As[lk + 5][lr] = a1.y;
    As[lk + 6][lr] = a1.z; As[lk + 7][lr] = a1.w;
    Bs[lk + 0][lr] = b0.x; Bs[lk + 1][lr] = b0.y;
    Bs[lk + 2][lr] = b0.z; Bs[lk + 3][lr] = b0.w;
    Bs[lk + 4][lr] = b1.x; Bs[lk + 5][lr] = b1.y;
    Bs[lk + 6][lr] = b1.z; Bs[lk + 7][lr] = b1.w;
    __syncthreads();
#pragma unroll
    for (int k = 0; k < 32; ++k) {
      float4 av = *reinterpret_cast<const float4*>(&As[k][ty * 4]);
      float4 bv = *reinterpret_cast<const float4*>(&Bs[k][tx * 4]);
      float am[4] = {av.x, av.y, av.z, av.w};
      float bn[4] = {bv.x, bv.y, bv.z, bv.w};
#pragma unroll
      for (int i = 0; i < 4; ++i)
#pragma unroll
        for (int j = 0; j < 4; ++j) acc[i][j] = fmaf(am[i], bn[j], acc[i][j]);
    }
  }
#pragma unroll
  for (int i = 0; i < 4; ++i) {
    float4 o = make_float4(acc[i][0], acc[i][1], acc[i][2], acc[i][3]);
    *reinterpret_cast<float4*>(wx + (size_t)(m0 + ty * 4 + i) * HDIM + n0 +
                               tx * 4) = o;
  }
}

extern "C" void kernel_launch(void* const* d_in, const int* in_sizes, int n_in,
                              void* d_out, int out_size, void* d_ws,
                              size_t ws_size, hipStream_t stream) {
  const float* x = (const float*)d_in[0];      // [32,1000,256]
  const float* W = (const float*)d_in[1];      // [512,256]
  const float* V = (const float*)d_in[2];      // [512,512]
  const float* alpha = (const float*)d_in[3];  // [512]
  const float* vthr = (const float*)d_in[4];   // [512]
  float* out = (float*)d_out;                  // [32,1000,512]

  const size_t wx_b = (size_t)BATCH * TSTEPS * HDIM * 4;  // 65,536,000
  const size_t wh_b = (size_t)HDIM * KDIM * 2;            //    262,144 (each)
  const size_t cb_b = (size_t)NSEG * BATCH * HDIM * 4;    //    524,288
  const size_t needA = wx_b + 2 * wh_b + cb_b + 128;      // ~66.6 MB
  const size_t needB = wx_b + cb_b + 128;

  char* ws = (char*)d_ws;
  if (ws_size >= needA) {
    float* wx = (float*)ws;
    unsigned short* wph = (unsigned short*)(ws + wx_b);
    unsigned short* wpl = wph + (size_t)HDIM * KDIM;
    float* cbuf = (float*)(ws + wx_b + 2 * wh_b);
    int* fs = (int*)(ws + wx_b + 2 * wh_b + cb_b);

    hipLaunchKernelGGL(init_fs, dim3(1), dim3(64), 0, stream, fs);
    hipLaunchKernelGGL(cast_pack, dim3(8), dim3(256), 0, stream, W, wph, wpl,
                       HDIM / 16);
    hipLaunchKernelGGL(gemm_mfma, dim3(BATCH * TSTEPS / 128), dim3(256), 0,
                       stream, x, wph, wpl, wx);
    hipLaunchKernelGGL(seg_sum, dim3(BATCH * NSEG * 8), dim3(64), 0, stream,
                       wx, alpha, cbuf);
    hipLaunchKernelGGL(seg_scan, dim3(BATCH * NSEG * 8), dim3(64), 0, stream,
                       wx, alpha, vthr, cbuf, out, fs);
    hipLaunchKernelGGL(fallback_scan, dim3(BATCH), dim3(64), 0, stream, wx, V,
                       alpha, vthr, out, fs);
  } else if (ws_size >= needB) {
    float* wx = (float*)ws;
    float* cbuf = (float*)(ws + wx_b);
    int* fs = (int*)(ws + wx_b + cb_b);
    hipLaunchKernelGGL(init_fs, dim3(1), dim3(64), 0, stream, fs);
    hipLaunchKernelGGL(gemm_xwT, dim3(BATCH * TSTEPS / 64, HDIM / 64),
                       dim3(256), 0, stream, x, W, wx);
    hipLaunchKernelGGL(seg_sum, dim3(BATCH * NSEG * 8), dim3(64), 0, stream,
                       wx, alpha, cbuf);
    hipLaunchKernelGGL(seg_scan, dim3(BATCH * NSEG * 8), dim3(64), 0, stream,
                       wx, alpha, vthr, cbuf, out, fs);
    hipLaunchKernelGGL(fallback_scan, dim3(BATCH), dim3(64), 0, stream, wx, V,
                       alpha, vthr, out, fs);
  } else {
    float* wx = (ws_size >= wx_b) ? (float*)ws : out;
    hipLaunchKernelGGL(gemm_xwT, dim3(BATCH * TSTEPS / 64, HDIM / 64),
                       dim3(256), 0, stream, x, W, wx);
    hipLaunchKernelGGL(rlif_scan, dim3(BATCH), dim3(64), 0, stream, wx, V,
                       alpha, vthr, out);
  }
}

// Round 7
// 79.258 us; speedup vs baseline: 3.8055x; 1.0642x over previous
//
#include <hip/hip_runtime.h>

// Problem constants (from reference setup_inputs): B=32, T=1000, I=256, H=512
#define BATCH 32
#define TSTEPS 1000
#define KDIM 256
#define HDIM 512
#define NSEG 8    // T-segments for the parallel scan
#define SEGL 125  // TSTEPS / NSEG
#define SPFD 25   // prefetch depth; SEGL % SPFD == 0 (REQUIRED: unrolled tail)

#define ALPHA_MIN_F 0.8187307530779818f
#define ALPHA_MAX_F 0.9607894391523232f

typedef __attribute__((ext_vector_type(8))) short bf16x8;          // 8 bf16
typedef __attribute__((ext_vector_type(8))) unsigned short u16x8;  // 16B store
typedef __attribute__((ext_vector_type(4))) float f32x4;

static __device__ __forceinline__ unsigned short f2bf(float f) {
  unsigned u = __float_as_uint(f);
  u += 0x7FFF + ((u >> 16) & 1);  // round-to-nearest-even
  return (unsigned short)(u >> 16);
}
static __device__ __forceinline__ float bf2f(unsigned short s) {
  return __uint_as_float(((unsigned)s) << 16);
}

__global__ void init_fs(int* fs) {
  if (threadIdx.x < BATCH) fs[threadIdx.x] = TSTEPS;
}

// ---------------------------------------------------------------------------
// Split-cast + fragment pack (round-5-proven; used for W only):
// packed[((tile*8+ks)*64+lane)*8+e] = src[tile*16+(lane&15)][(lane>>4)*8+ks*32+e]
// ---------------------------------------------------------------------------
__global__ __launch_bounds__(256) void cast_pack(const float* __restrict__ src,
                                                 unsigned short* __restrict__ hi,
                                                 unsigned short* __restrict__ lo,
                                                 int ntiles) {
  const int tile = blockIdx.x * 4 + (threadIdx.x >> 6);
  if (tile >= ntiles) return;
  const int lane = threadIdx.x & 63;
  const int row = tile * 16 + (lane & 15);
  const int kg = lane >> 4;
  const float* sp = src + (size_t)row * KDIM + kg * 8;
  unsigned short* hp = hi + (size_t)tile * 8 * 512 + lane * 8;
  unsigned short* lp = lo + (size_t)tile * 8 * 512 + lane * 8;
#pragma unroll
  for (int ks = 0; ks < 8; ++ks) {
    float4 a = *reinterpret_cast<const float4*>(sp + ks * 32);
    float4 b = *reinterpret_cast<const float4*>(sp + ks * 32 + 4);
    u16x8 h, l;
    h[0] = f2bf(a.x); l[0] = f2bf(a.x - bf2f(h[0]));
    h[1] = f2bf(a.y); l[1] = f2bf(a.y - bf2f(h[1]));
    h[2] = f2bf(a.z); l[2] = f2bf(a.z - bf2f(h[2]));
    h[3] = f2bf(a.w); l[3] = f2bf(a.w - bf2f(h[3]));
    h[4] = f2bf(b.x); l[4] = f2bf(b.x - bf2f(h[4]));
    h[5] = f2bf(b.y); l[5] = f2bf(b.y - bf2f(h[5]));
    h[6] = f2bf(b.z); l[6] = f2bf(b.z - bf2f(h[6]));
    h[7] = f2bf(b.w); l[7] = f2bf(b.w - bf2f(h[7]));
    *reinterpret_cast<u16x8*>(hp + ks * 512) = h;
    *reinterpret_cast<u16x8*>(lp + ks * 512) = l;
  }
}

// ---------------------------------------------------------------------------
// MFMA GEMM: wx[m][n] = sum_k x[m][k]*W[n][k], 3-pass bf16 split (hh+lh+hl).
// Round-7 schedule fix (no semantic change):
//   - grid 500 (1 m-tile per wave) -> ~2 blocks/CU = 2 waves/SIMD;
//   - 3 SEPARATE accumulators (hh, lh, hl; summed in epilogue) -> 3
//     independent 8-deep MFMA chains per wave (6 per SIMD) instead of 2
//     12-deep chains -> matrix pipe stays fed.
// A: direct from f32 x, split in-registers (proven k-map: k=(lane>>4)*8+ks*32+e).
// B: packed W staged per n-tile into LDS (double-buffered, issue-early /
//    write-late; proven round-6 pattern, byte-identical).
// C/D mapping (m89-verified): col=lane&15, row=4*(lane>>4)+reg.
// ---------------------------------------------------------------------------
__global__ __launch_bounds__(256, 1) void gemm_mfma(
    const float* __restrict__ x, const unsigned short* __restrict__ wph,
    const unsigned short* __restrict__ wpl, float* __restrict__ wx) {
  __shared__ short bsh[2][2][4096];  // [buf][hi/lo][ks*512 + lane*8 + e], 32KB
  const int tid = threadIdx.x;
  const int lane = tid & 63;
  const int wid = tid >> 6;
  const int row = lane & 15;
  const int kg = lane >> 4;
  const int tm = blockIdx.x * 4 + wid;  // this wave's single m-tile
  const int m0 = tm * 16;
  const int tO = tid * 8;  // staging offset in shorts (0..2040)

  // A fragments: 8 ks, hi & lo, split from f32 in-registers.
  bf16x8 ah[8], al[8];
  const float* xp = x + (size_t)(m0 + row) * KDIM + kg * 8;
#pragma unroll
  for (int ks = 0; ks < 8; ++ks) {
    float4 f0 = *reinterpret_cast<const float4*>(xp + ks * 32);
    float4 f1 = *reinterpret_cast<const float4*>(xp + ks * 32 + 4);
    bf16x8 hv, lv;
    hv[0] = (short)f2bf(f0.x); lv[0] = (short)f2bf(f0.x - bf2f(hv[0]));
    hv[1] = (short)f2bf(f0.y); lv[1] = (short)f2bf(f0.y - bf2f(hv[1]));
    hv[2] = (short)f2bf(f0.z); lv[2] = (short)f2bf(f0.z - bf2f(hv[2]));
    hv[3] = (short)f2bf(f0.w); lv[3] = (short)f2bf(f0.w - bf2f(hv[3]));
    hv[4] = (short)f2bf(f1.x); lv[4] = (short)f2bf(f1.x - bf2f(hv[4]));
    hv[5] = (short)f2bf(f1.y); lv[5] = (short)f2bf(f1.y - bf2f(hv[5]));
    hv[6] = (short)f2bf(f1.z); lv[6] = (short)f2bf(f1.z - bf2f(hv[6]));
    hv[7] = (short)f2bf(f1.w); lv[7] = (short)f2bf(f1.w - bf2f(hv[7]));
    ah[ks] = hv;
    al[ks] = lv;
  }

  // Prologue: stage n-tile 0 into buf 0.
  {
    *reinterpret_cast<bf16x8*>(&bsh[0][0][tO]) =
        *reinterpret_cast<const bf16x8*>(wph + tO);
    *reinterpret_cast<bf16x8*>(&bsh[0][0][2048 + tO]) =
        *reinterpret_cast<const bf16x8*>(wph + 2048 + tO);
    *reinterpret_cast<bf16x8*>(&bsh[0][1][tO]) =
        *reinterpret_cast<const bf16x8*>(wpl + tO);
    *reinterpret_cast<bf16x8*>(&bsh[0][1][2048 + tO]) =
        *reinterpret_cast<const bf16x8*>(wpl + 2048 + tO);
  }
  __syncthreads();

  for (int ct = 0; ct < 32; ++ct) {
    const int buf = ct & 1;
    // Issue next tile's global loads early (latency hidden under MFMAs).
    bf16x8 nh0, nh1, nl0, nl1;
    const bool pre = (ct < 31);
    if (pre) {
      const unsigned short* sh = wph + (size_t)(ct + 1) * 4096;
      const unsigned short* sl = wpl + (size_t)(ct + 1) * 4096;
      nh0 = *reinterpret_cast<const bf16x8*>(sh + tO);
      nh1 = *reinterpret_cast<const bf16x8*>(sh + 2048 + tO);
      nl0 = *reinterpret_cast<const bf16x8*>(sl + tO);
      nl1 = *reinterpret_cast<const bf16x8*>(sl + 2048 + tO);
    }

    f32x4 accA = {0.f, 0.f, 0.f, 0.f};  // hh
    f32x4 accB = {0.f, 0.f, 0.f, 0.f};  // lh
    f32x4 accC = {0.f, 0.f, 0.f, 0.f};  // hl
#pragma unroll
    for (int ks = 0; ks < 8; ++ks) {
      bf16x8 bh = *reinterpret_cast<const bf16x8*>(&bsh[buf][0][ks * 512 + lane * 8]);
      bf16x8 bl = *reinterpret_cast<const bf16x8*>(&bsh[buf][1][ks * 512 + lane * 8]);
      accA = __builtin_amdgcn_mfma_f32_16x16x32_bf16(ah[ks], bh, accA, 0, 0, 0);
      accB = __builtin_amdgcn_mfma_f32_16x16x32_bf16(al[ks], bh, accB, 0, 0, 0);
      accC = __builtin_amdgcn_mfma_f32_16x16x32_bf16(ah[ks], bl, accC, 0, 0, 0);
    }
    const int n0 = ct * 16;
#pragma unroll
    for (int j = 0; j < 4; ++j) {
      wx[(size_t)(m0 + kg * 4 + j) * HDIM + n0 + row] =
          (accA[j] + accB[j]) + accC[j];
    }
    if (pre) {  // write-late into the other buffer
      *reinterpret_cast<bf16x8*>(&bsh[buf ^ 1][0][tO]) = nh0;
      *reinterpret_cast<bf16x8*>(&bsh[buf ^ 1][0][2048 + tO]) = nh1;
      *reinterpret_cast<bf16x8*>(&bsh[buf ^ 1][1][tO]) = nl0;
      *reinterpret_cast<bf16x8*>(&bsh[buf ^ 1][1][2048 + tO]) = nl1;
    }
    __syncthreads();
  }
}

// ---------------------------------------------------------------------------
// Pass A: per-(b,seg,h) particular solution of the LINEAR recurrence over the
// segment: c = sum_j a^(SEGL-1-j) * na * w_j, computed by the same iteration
// c = fma(a, c, na*w). 2048 waves -> BW-bound.
// ---------------------------------------------------------------------------
__global__ __launch_bounds__(64) void seg_sum(const float* __restrict__ wx,
                                              const float* __restrict__ alpha,
                                              float* __restrict__ cbuf) {
  const int hb = blockIdx.x & 7;
  const int seg = (blockIdx.x >> 3) & 7;
  const int b = blockIdx.x >> 6;
  const int h = (hb << 6) + threadIdx.x;
  const float a = fminf(fmaxf(alpha[h], ALPHA_MIN_F), ALPHA_MAX_F);
  const float na = 1.0f - a;
  const float* wp = wx + ((size_t)b * TSTEPS + seg * SEGL) * HDIM + h;

  float pf[SPFD];
#pragma unroll
  for (int d = 0; d < SPFD; ++d) pf[d] = wp[(size_t)d * HDIM];

  float c = 0.f;
  for (int j0 = 0; j0 < SEGL; j0 += SPFD) {
#pragma unroll
    for (int js = 0; js < SPFD; ++js) {
      const int j = j0 + js;
      const float w = pf[js];
      int jp = j + SPFD;
      if (jp > SEGL - 1) jp = SEGL - 1;  // clamped in-segment tail reload
      pf[js] = wp[(size_t)jp * HDIM];
      c = fmaf(a, c, na * w);
    }
  }
  cbuf[(size_t)seg * BATCH * HDIM + (size_t)b * HDIM + h] = c;
}

// ---------------------------------------------------------------------------
// Pass B: reconstruct the linear boundary state u_start = fold_k fma(a^SEGL,
// u, c_k), then run the NONLINEAR per-channel dynamics (self-reset, r=0) for
// the segment. Exact (to ulp) up to the batch's first true spike t*: before
// t* the true dynamics are linear, so every segment start below/at t* is
// right, t* is detected exactly via atomicMin, and spurious later spikes
// cannot lower the min. Spiking batches are rewritten by fallback_scan.
// ---------------------------------------------------------------------------
__global__ __launch_bounds__(64) void seg_scan(const float* __restrict__ wx,
                                               const float* __restrict__ alpha,
                                               const float* __restrict__ vthr,
                                               const float* __restrict__ cbuf,
                                               float* __restrict__ out,
                                               int* __restrict__ fs) {
  const int hb = blockIdx.x & 7;
  const int seg = (blockIdx.x >> 3) & 7;
  const int b = blockIdx.x >> 6;
  const int h = (hb << 6) + threadIdx.x;
  const float a = fminf(fmaxf(alpha[h], ALPHA_MIN_F), ALPHA_MAX_F);
  const float na = 1.0f - a;
  const float th = vthr[h];
  const int t0g = seg * SEGL;
  const float* wp = wx + ((size_t)b * TSTEPS + t0g) * HDIM + h;
  float* op = out + ((size_t)b * TSTEPS + t0g) * HDIM + h;

  // Issue the prefetch pipeline first so it overlaps the u_start computation.
  float pf[SPFD];
#pragma unroll
  for (int d = 0; d < SPFD; ++d) pf[d] = wp[(size_t)d * HDIM];

  // a^SEGL (serial mults; ~ulp-accurate on a tiny factor, error << threshold)
  float aL = 1.0f;
  for (int i = 0; i < SEGL; ++i) aL *= a;
  float u = 0.f;
  for (int k = 0; k < seg; ++k)  // wave-uniform bound (seg is block-wide)
    u = fmaf(aL, u, cbuf[(size_t)k * BATCH * HDIM + (size_t)b * HDIM + h]);

  float s = 0.f;
  int first = TSTEPS;
  for (int j0 = 0; j0 < SEGL; j0 += SPFD) {
#pragma unroll
    for (int js = 0; js < SPFD; ++js) {
      const int j = j0 + js;
      const float w = pf[js];
      int jp = j + SPFD;
      if (jp > SEGL - 1) jp = SEGL - 1;  // clamped in-segment tail reload
      pf[js] = wp[(size_t)jp * HDIM];
      u = fmaf(a, u - s, na * w);
      s = (u > th) ? 1.0f : 0.0f;
      op[(size_t)j * HDIM] = s;
      if (s != 0.0f && first == TSTEPS) {
        first = t0g + j;
        atomicMin(&fs[b], first);
      }
    }
  }
}

// ---------------------------------------------------------------------------
// Full coupled scan body (round-1-proven): one wave per batch, sparse s@Vz
// via ballot. Used gated (fallback) and ungated (tiny-ws tier).
// ---------------------------------------------------------------------------
static __device__ __forceinline__ void scan_body(const float* wxbuf,
                                                 const float* __restrict__ V,
                                                 const float* __restrict__ alpha,
                                                 const float* __restrict__ vthr,
                                                 float* out, int b) {
  const int l = threadIdx.x;
  const int h0 = 4 * l;
  const int h1 = 256 + 4 * l;

  float4 al0 = *reinterpret_cast<const float4*>(alpha + h0);
  float4 al1 = *reinterpret_cast<const float4*>(alpha + h1);
  float4 th0 = *reinterpret_cast<const float4*>(vthr + h0);
  float4 th1 = *reinterpret_cast<const float4*>(vthr + h1);
  float a[8] = {al0.x, al0.y, al0.z, al0.w, al1.x, al1.y, al1.z, al1.w};
  float th[8] = {th0.x, th0.y, th0.z, th0.w, th1.x, th1.y, th1.z, th1.w};
  float na[8], u[8], s[8], r[8];
#pragma unroll
  for (int j = 0; j < 8; ++j) {
    float c = fminf(fmaxf(a[j], ALPHA_MIN_F), ALPHA_MAX_F);
    a[j] = c; na[j] = 1.0f - c;
    u[j] = 0.f; s[j] = 0.f; r[j] = 0.f;
  }
  const float* wb = wxbuf + (size_t)b * TSTEPS * HDIM;
  float* ob = out + (size_t)b * TSTEPS * HDIM;
  float4 p0[4], p1[4];
#pragma unroll
  for (int d = 0; d < 4; ++d) {
    p0[d] = *reinterpret_cast<const float4*>(wb + (size_t)d * HDIM + h0);
    p1[d] = *reinterpret_cast<const float4*>(wb + (size_t)d * HDIM + h1);
  }
  for (int t0 = 0; t0 < TSTEPS; t0 += 4) {
#pragma unroll
    for (int ts = 0; ts < 4; ++ts) {
      const int t = t0 + ts;
      float w8[8] = {p0[ts].x, p0[ts].y, p0[ts].z, p0[ts].w,
                     p1[ts].x, p1[ts].y, p1[ts].z, p1[ts].w};
      int tpre = t + 4;
      if (tpre > TSTEPS - 1) tpre = TSTEPS - 1;
      p0[ts] = *reinterpret_cast<const float4*>(wb + (size_t)tpre * HDIM + h0);
      p1[ts] = *reinterpret_cast<const float4*>(wb + (size_t)tpre * HDIM + h1);
#pragma unroll
      for (int j = 0; j < 8; ++j) {
        float un = fmaf(a[j], u[j] - s[j], na[j] * (w8[j] + r[j]));
        u[j] = un;
        s[j] = (un > th[j]) ? 1.0f : 0.0f;
      }
      *reinterpret_cast<float4*>(ob + (size_t)t * HDIM + h0) =
          make_float4(s[0], s[1], s[2], s[3]);
      *reinterpret_cast<float4*>(ob + (size_t)t * HDIM + h1) =
          make_float4(s[4], s[5], s[6], s[7]);
      float ssum = s[0] + s[1] + s[2] + s[3] + s[4] + s[5] + s[6] + s[7];
      unsigned long long anym = __ballot(ssum != 0.0f);
      if (anym != 0ull) {
        unsigned long long mk[8];
#pragma unroll
        for (int j = 0; j < 8; ++j) mk[j] = __ballot(s[j] != 0.0f);
        float rr[8] = {0.f, 0.f, 0.f, 0.f, 0.f, 0.f, 0.f, 0.f};
#pragma unroll
        for (int j2 = 0; j2 < 8; ++j2) {
          unsigned long long m = mk[j2];
          while (m) {  // wave-uniform (masks identical on all lanes)
            int src = __builtin_ctzll(m);
            m &= m - 1;
            int hin = (j2 < 4) ? (src * 4 + j2) : (256 + src * 4 + (j2 - 4));
            const float* vrow = V + (size_t)hin * HDIM;
            float4 v0 = *reinterpret_cast<const float4*>(vrow + h0);
            float4 v1 = *reinterpret_cast<const float4*>(vrow + h1);
            float vv[8] = {v0.x, v0.y, v0.z, v0.w, v1.x, v1.y, v1.z, v1.w};
#pragma unroll
            for (int j = 0; j < 8; ++j) {
              int hj = (j < 4) ? (h0 + j) : (h1 + j - 4);
              rr[j] += (hj == hin) ? 0.0f : vv[j];  // zeroed diagonal
            }
          }
        }
#pragma unroll
        for (int j = 0; j < 8; ++j) r[j] = rr[j];
      } else {
#pragma unroll
        for (int j = 0; j < 8; ++j) r[j] = 0.0f;
      }
    }
  }
}

// Gated fallback: only batches whose first spike is at t <= TSTEPS-2 need the
// coupled recompute (a spike at the last step cannot affect any output).
__global__ __launch_bounds__(64) void fallback_scan(
    const float* wxbuf, const float* __restrict__ V,
    const float* __restrict__ alpha, const float* __restrict__ vthr,
    float* out, const int* __restrict__ fs) {
  const int b = blockIdx.x;
  if (fs[b] >= TSTEPS - 1) return;
  scan_body(wxbuf, V, alpha, vthr, out, b);
}

// Ungated (tiny-ws tier, round-1 semantics).
__global__ __launch_bounds__(64) void rlif_scan(const float* wxbuf,
                                                const float* __restrict__ V,
                                                const float* __restrict__ alpha,
                                                const float* __restrict__ vthr,
                                                float* out) {
  scan_body(wxbuf, V, alpha, vthr, out, blockIdx.x);
}

// ---------------------------------------------------------------------------
// Tier-B f32 GEMM (round-1-proven).
// ---------------------------------------------------------------------------
__global__ __launch_bounds__(256) void gemm_xwT(const float* __restrict__ x,
                                                const float* __restrict__ W,
                                                float* __restrict__ wx) {
  __shared__ float As[32][64];
  __shared__ float Bs[32][64];
  const int m0 = blockIdx.x * 64;
  const int n0 = blockIdx.y * 64;
  const int tid = threadIdx.x;
  const int tx = tid & 15;
  const int ty = tid >> 4;
  const int lr = tid >> 2;
  const int lk = (tid & 3) * 8;

  float acc[4][4] = {};
  for (int k0 = 0; k0 < KDIM; k0 += 32) {
    const float4* ap =
        reinterpret_cast<const float4*>(x + (size_t)(m0 + lr) * KDIM + k0 + lk);
    const float4* bp =
        reinterpret_cast<const float4*>(W + (size_t)(n0 + lr) * KDIM + k0 + lk);
    float4 a0 = ap[0], a1 = ap[1];
    float4 b0 = bp[0], b1 = bp[1];
    __syncthreads();
    As[lk + 0][lr] = a0.x; As[lk + 1][lr] = a0.y;
    As[lk + 2][lr] = a0.z; As[lk + 3][lr] = a0.w;
    As[lk + 4][lr] = a1.x; As[lk + 5][lr] = a1.y;
    As[lk + 6][lr] = a1.z; As[lk + 7][lr] = a1.w;
    Bs[lk + 0][lr] = b0.x; Bs[lk + 1][lr] = b0.y;
    Bs[lk + 2][lr] = b0.z; Bs[lk + 3][lr] = b0.w;
    Bs[lk + 4][lr] = b1.x; Bs[lk + 5][lr] = b1.y;
    Bs[lk + 6][lr] = b1.z; Bs[lk + 7][lr] = b1.w;
    __syncthreads();
#pragma unroll
    for (int k = 0; k < 32; ++k) {
      float4 av = *reinterpret_cast<const float4*>(&As[k][ty * 4]);
      float4 bv = *reinterpret_cast<const float4*>(&Bs[k][tx * 4]);
      float am[4] = {av.x, av.y, av.z, av.w};
      float bn[4] = {bv.x, bv.y, bv.z, bv.w};
#pragma unroll
      for (int i = 0; i < 4; ++i)
#pragma unroll
        for (int j = 0; j < 4; ++j) acc[i][j] = fmaf(am[i], bn[j], acc[i][j]);
    }
  }
#pragma unroll
  for (int i = 0; i < 4; ++i) {
    float4 o = make_float4(acc[i][0], acc[i][1], acc[i][2], acc[i][3]);
    *reinterpret_cast<float4*>(wx + (size_t)(m0 + ty * 4 + i) * HDIM + n0 +
                               tx * 4) = o;
  }
}

extern "C" void kernel_launch(void* const* d_in, const int* in_sizes, int n_in,
                              void* d_out, int out_size, void* d_ws,
                              size_t ws_size, hipStream_t stream) {
  const float* x = (const float*)d_in[0];      // [32,1000,256]
  const float* W = (const float*)d_in[1];      // [512,256]
  const float* V = (const float*)d_in[2];      // [512,512]
  const float* alpha = (const float*)d_in[3];  // [512]
  const float* vthr = (const float*)d_in[4];   // [512]
  float* out = (float*)d_out;                  // [32,1000,512]

  const size_t wx_b = (size_t)BATCH * TSTEPS * HDIM * 4;  // 65,536,000
  const size_t wh_b = (size_t)HDIM * KDIM * 2;            //    262,144 (each)
  const size_t cb_b = (size_t)NSEG * BATCH * HDIM * 4;    //    524,288
  const size_t needA = wx_b + 2 * wh_b + cb_b + 128;      // ~66.6 MB
  const size_t needB = wx_b + cb_b + 128;

  char* ws = (char*)d_ws;
  if (ws_size >= needA) {
    float* wx = (float*)ws;
    unsigned short* wph = (unsigned short*)(ws + wx_b);
    unsigned short* wpl = wph + (size_t)HDIM * KDIM;
    float* cbuf = (float*)(ws + wx_b + 2 * wh_b);
    int* fs = (int*)(ws + wx_b + 2 * wh_b + cb_b);

    hipLaunchKernelGGL(init_fs, dim3(1), dim3(64), 0, stream, fs);
    hipLaunchKernelGGL(cast_pack, dim3(8), dim3(256), 0, stream, W, wph, wpl,
                       HDIM / 16);
    // 2000 m-tiles, 4 per block (1 per wave) -> 500 blocks ~ 2 blocks/CU
    hipLaunchKernelGGL(gemm_mfma, dim3(BATCH * TSTEPS / 64), dim3(256), 0,
                       stream, x, wph, wpl, wx);
    hipLaunchKernelGGL(seg_sum, dim3(BATCH * NSEG * 8), dim3(64), 0, stream,
                       wx, alpha, cbuf);
    hipLaunchKernelGGL(seg_scan, dim3(BATCH * NSEG * 8), dim3(64), 0, stream,
                       wx, alpha, vthr, cbuf, out, fs);
    hipLaunchKernelGGL(fallback_scan, dim3(BATCH), dim3(64), 0, stream, wx, V,
                       alpha, vthr, out, fs);
  } else if (ws_size >= needB) {
    float* wx = (float*)ws;
    float* cbuf = (float*)(ws + wx_b);
    int* fs = (int*)(ws + wx_b + cb_b);
    hipLaunchKernelGGL(init_fs, dim3(1), dim3(64), 0, stream, fs);
    hipLaunchKernelGGL(gemm_xwT, dim3(BATCH * TSTEPS / 64, HDIM / 64),
                       dim3(256), 0, stream, x, W, wx);
    hipLaunchKernelGGL(seg_sum, dim3(BATCH * NSEG * 8), dim3(64), 0, stream,
                       wx, alpha, cbuf);
    hipLaunchKernelGGL(seg_scan, dim3(BATCH * NSEG * 8), dim3(64), 0, stream,
                       wx, alpha, vthr, cbuf, out, fs);
    hipLaunchKernelGGL(fallback_scan, dim3(BATCH), dim3(64), 0, stream, wx, V,
                       alpha, vthr, out, fs);
  } else {
    float* wx = (ws_size >= wx_b) ? (float*)ws : out;
    hipLaunchKernelGGL(gemm_xwT, dim3(BATCH * TSTEPS / 64, HDIM / 64),
                       dim3(256), 0, stream, x, W, wx);
    hipLaunchKernelGGL(rlif_scan, dim3(BATCH), dim3(64), 0, stream, wx, V,
                       alpha, vthr, out);
  }
}